// Round 12
// baseline (2742.314 us; speedup 1.0000x reference)
//
#include <hip/hip_runtime.h>
#include <hip/hip_fp16.h>

#define NN 262144
#define EE 1048576
#define GG 8192
#define HH 128
#define FBc 3
#define VAc 64
#define VBc 8
#define FAc 9

typedef _Float16 f16;
typedef _Float16 f16x8 __attribute__((ext_vector_type(8)));
typedef float f32x4 __attribute__((ext_vector_type(4)));

__device__ __forceinline__ float h2f(ushort u) {
    __half h; *(ushort*)&h = u; return __half2float(h);
}
__device__ __forceinline__ ushort f2h(float f) {
    __half h = __float2half_rn(f); return *(ushort*)&h;
}

// ---------------- zero fill ----------------
__global__ void k_zero(float* __restrict__ p) {
    size_t i = (size_t)(blockIdx.x * 256 + threadIdx.x) * 4;
    *(float4*)(p + i) = make_float4(0.f, 0.f, 0.f, 0.f);
}

// ---------------- atom encoder: h16 = (sum emb)/16 fp16 ----------------
__global__ void k_atom(const int* __restrict__ x, const float* __restrict__ emb,
                       ushort* __restrict__ h16) {
    int t = blockIdx.x * 256 + threadIdx.x;
    int n = t >> 5, c = (t & 31) << 2;
    if (n >= NN) return;
    float4 a = make_float4(0.f, 0.f, 0.f, 0.f);
#pragma unroll
    for (int f = 0; f < FAc; ++f) {
        int v = x[n * FAc + f];
        float4 e = *(const float4*)(emb + ((size_t)(f * VAc + v)) * HH + c);
        a.x += e.x; a.y += e.y; a.z += e.z; a.w += e.w;
    }
    ushort4 o;
    o.x = f2h(a.x * 0.0625f); o.y = f2h(a.y * 0.0625f);
    o.z = f2h(a.z * 0.0625f); o.w = f2h(a.w * 0.0625f);
    *(ushort4*)(h16 + (size_t)n * HH + c) = o;
}

// ---------------- vn init ----------------
__global__ void k_init_vn(const float* __restrict__ vn_emb, float* __restrict__ vn) {
    int t = blockIdx.x * 256 + threadIdx.x;
    int g = t >> 5, c = (t & 31) << 2;
    *(float4*)(vn + (size_t)g * HH + c) = *(const float4*)(vn_emb + c);
}

// ---------------- vn16 = vn/16 fp16 ----------------
__global__ void k_vn16(const float* __restrict__ vn, ushort* __restrict__ vn16) {
    int t = blockIdx.x * 256 + threadIdx.x;
    float4 v = *(const float4*)(vn + (size_t)t * 4);
    ushort4 o;
    o.x = f2h(v.x * 0.0625f); o.y = f2h(v.y * 0.0625f);
    o.z = f2h(v.z * 0.0625f); o.w = f2h(v.w * 0.0625f);
    *(ushort4*)(vn16 + (size_t)t * 4) = o;
}

// ================= CSR build =================
__global__ void k_hist(const int* __restrict__ ei, int* __restrict__ deg) {
    int e = blockIdx.x * 256 + threadIdx.x;
    atomicAdd(&deg[ei[EE + e]], 1);
}
__global__ void k_scan1(const int* __restrict__ deg, int* __restrict__ rowptr,
                        int* __restrict__ sums) {
    __shared__ int s[256];
    int base = blockIdx.x * 1024 + threadIdx.x * 4;
    int4 d = *(const int4*)(deg + base);
    int t = d.x + d.y + d.z + d.w;
    s[threadIdx.x] = t;
    __syncthreads();
    for (int off = 1; off < 256; off <<= 1) {
        int v = (threadIdx.x >= off) ? s[threadIdx.x - off] : 0;
        __syncthreads();
        s[threadIdx.x] += v;
        __syncthreads();
    }
    int excl = s[threadIdx.x] - t;
    int4 o; o.x = excl; o.y = excl + d.x; o.z = o.y + d.y; o.w = o.z + d.z;
    *(int4*)(rowptr + base) = o;
    if (threadIdx.x == 255) sums[blockIdx.x] = s[255];
}
__global__ void k_scan2(int* __restrict__ sums) {
    __shared__ int s[256];
    int t = sums[threadIdx.x];
    s[threadIdx.x] = t;
    __syncthreads();
    for (int off = 1; off < 256; off <<= 1) {
        int v = (threadIdx.x >= off) ? s[threadIdx.x - off] : 0;
        __syncthreads();
        s[threadIdx.x] += v;
        __syncthreads();
    }
    sums[threadIdx.x] = s[threadIdx.x] - t;
}
__global__ void k_scan3(int* __restrict__ rowptr, const int* __restrict__ sums,
                        int* __restrict__ fill) {
    int base = blockIdx.x * 1024 + threadIdx.x * 4;
    int add = sums[blockIdx.x];
    int4 r = *(const int4*)(rowptr + base);
    r.x += add; r.y += add; r.z += add; r.w += add;
    *(int4*)(rowptr + base) = r;
    *(int4*)(fill + base) = r;
    if (blockIdx.x == 0 && threadIdx.x == 0) rowptr[NN] = EE;
}
__global__ void k_scatter(const int* __restrict__ ei, const int* __restrict__ ea,
                          int* __restrict__ fill, unsigned* __restrict__ packed) {
    int e = blockIdx.x * 256 + threadIdx.x;
    int dst = ei[EE + e];
    int pos = atomicAdd(&fill[dst], 1);
    unsigned cb = (unsigned)(ea[e * 3 + 0] + ea[e * 3 + 1] * 8 + ea[e * 3 + 2] * 64);
    packed[pos] = (unsigned)ei[e] | (cb << 18);
}

// per-layer bond-combo table
__global__ void k_ctab(const float* __restrict__ bemb, float* __restrict__ ctab) {
    int t = blockIdx.x * 256 + threadIdx.x;
    int cb = t >> 5, c = (t & 31) << 2;
    int a0 = cb & 7, a1 = (cb >> 3) & 7, a2 = cb >> 6;
    float4 b0 = *(const float4*)(bemb + (size_t)(0 * VBc + a0) * HH + c);
    float4 b1 = *(const float4*)(bemb + (size_t)(1 * VBc + a1) * HH + c);
    float4 b2 = *(const float4*)(bemb + (size_t)(2 * VBc + a2) * HH + c);
    float4 o = make_float4(b0.x + b1.x + b2.x, b0.y + b1.y + b2.y,
                           b0.z + b1.z + b2.z, b0.w + b1.w + b2.w);
    *(float4*)(ctab + (size_t)cb * HH + c) = o;
}

// per-layer folded BN tables
__global__ void k_prep(const float* __restrict__ b1, const float* __restrict__ g1,
                       const float* __restrict__ be1, const float* __restrict__ m1,
                       const float* __restrict__ v1,
                       const float* __restrict__ g3, const float* __restrict__ be3,
                       const float* __restrict__ m3, const float* __restrict__ v3,
                       float* __restrict__ ZA, float* __restrict__ ZB,
                       float* __restrict__ TA, float* __restrict__ TB,
                       float* __restrict__ S3) {
    int c = threadIdx.x;   // 256
    float s1 = g1[c] * rsqrtf(v1[c] + 1e-5f);
    ZA[c] = s1;
    ZB[c] = ((b1[c] - m1[c]) * s1 + be1[c]) * 0.0625f;
    float s3 = g3[c] * rsqrtf(v3[c] + 1e-5f);
    TA[c] = 16.f * s3;
    TB[c] = be3[c] - m3[c] * s3;
    S3[c] = s3;
}

// weight transpose: W [K][Nsrc] f32 -> Wt [N][K] fp16
__global__ void k_wt(const float* __restrict__ W, ushort* __restrict__ Wt, int lk, int Nsrc) {
    int o = blockIdx.x * 256 + threadIdx.x;
    int K = 1 << lk;
    int c = o >> lk, k = o & (K - 1);
    Wt[o] = f2h(W[(size_t)k * Nsrc + c]);
}

// CSR aggregation: agg[n] = (1/16) sum relu(16*(h16[src]+vn16[batch[src]])+ctab)
__global__ void k_agg(const ushort* __restrict__ h16, const ushort* __restrict__ vn16,
                      const int* __restrict__ batch,
                      const int* __restrict__ rowptr, const unsigned* __restrict__ packed,
                      const float* __restrict__ ctab, ushort* __restrict__ agg) {
    int n = blockIdx.x * 4 + (threadIdx.x >> 6);
    int lane = threadIdx.x & 63;
    int co = lane * 2;
    int beg = rowptr[n], end = rowptr[n + 1];
    float a0 = 0.f, a1 = 0.f;
    int i = beg;
    for (; i + 1 < end; i += 2) {
        unsigned p0 = packed[i], p1 = packed[i + 1];
        int s0 = p0 & 0x3FFFF, s1 = p1 & 0x3FFFF;
        int c0 = p0 >> 18, c1 = p1 >> 18;
        ushort2 u0 = *(const ushort2*)(h16 + (size_t)s0 * HH + co);
        ushort2 u1 = *(const ushort2*)(h16 + (size_t)s1 * HH + co);
        ushort2 w0 = *(const ushort2*)(vn16 + (size_t)batch[s0] * HH + co);
        ushort2 w1 = *(const ushort2*)(vn16 + (size_t)batch[s1] * HH + co);
        float2 t0 = *(const float2*)(ctab + (size_t)c0 * HH + co);
        float2 t1 = *(const float2*)(ctab + (size_t)c1 * HH + co);
        a0 += fmaxf(16.f * (h2f(u0.x) + h2f(w0.x)) + t0.x, 0.f)
            + fmaxf(16.f * (h2f(u1.x) + h2f(w1.x)) + t1.x, 0.f);
        a1 += fmaxf(16.f * (h2f(u0.y) + h2f(w0.y)) + t0.y, 0.f)
            + fmaxf(16.f * (h2f(u1.y) + h2f(w1.y)) + t1.y, 0.f);
    }
    if (i < end) {
        unsigned p = packed[i];
        int src = p & 0x3FFFF, cb = p >> 18;
        ushort2 u = *(const ushort2*)(h16 + (size_t)src * HH + co);
        ushort2 wv = *(const ushort2*)(vn16 + (size_t)batch[src] * HH + co);
        float2 ct = *(const float2*)(ctab + (size_t)cb * HH + co);
        a0 += fmaxf(16.f * (h2f(u.x) + h2f(wv.x)) + ct.x, 0.f);
        a1 += fmaxf(16.f * (h2f(u.y) + h2f(wv.y)) + ct.y, 0.f);
    }
    ushort2 o; o.x = f2h(a0 * 0.0625f); o.y = f2h(a1 * 0.0625f);
    *(ushort2*)(agg + (size_t)n * HH + co) = o;
}

// ============== mega-kernel v3: register fragments, 32 KB LDS, ~4 barriers ==============
// A and W operands feed MFMA straight from global (fragment-layout 16B loads).
// zs: z (cols 0-255) -> h'/16 (cols 0-127) -> t (cols 128-255). Rows wave-private.
// XOR swizzle at 16B-block granularity within each row: blk ^= (row & 7).
__global__ void __launch_bounds__(256, 4)
k_conv(ushort* __restrict__ h16, const ushort* __restrict__ agg,
       const ushort* __restrict__ W1t, const ushort* __restrict__ W2t,
       const ushort* __restrict__ W3t,
       const int* __restrict__ batch, const ushort* __restrict__ vn16,
       const float* __restrict__ vnW,
       const float* __restrict__ eps_ptr,
       const float* __restrict__ ZA, const float* __restrict__ ZB,
       const float* __restrict__ b2,
       const float* __restrict__ TA, const float* __restrict__ TB,
       float* __restrict__ pooled) {
    __shared__ ushort zs[64][256];    // 32 KB
    const int tid = threadIdx.x;
    const int r0 = blockIdx.x * 64;
    const int w = tid >> 6, l = tid & 63, lr = l & 15, lg = l >> 4, lr7 = lr & 7;
    const float eps1 = 1.f + eps_ptr[0];
    const int myrow = w * 16 + lr;                 // A-fragment local row
    const int growA = r0 + myrow;
    const int ggA = batch[growA];
    int rl[4], ggs[4];
#pragma unroll
    for (int reg = 0; reg < 4; ++reg) {
        rl[reg] = w * 16 + lg * 4 + reg;           // C/D local rows
        ggs[reg] = batch[r0 + rl[reg]];
    }

    // ---- A fragments (registers): A/16 = eps1*(h16+vn16) + agg16 ----
    f16x8 af[4];
#pragma unroll
    for (int k0 = 0; k0 < 4; ++k0) {
        int ko = k0 * 32 + lg * 8;
        f16x8 hv = *(const f16x8*)(h16 + (size_t)growA * HH + ko);
        f16x8 vv = *(const f16x8*)(vn16 + (size_t)ggA * HH + ko);
        f16x8 ag = *(const f16x8*)(agg + (size_t)growA * HH + ko);
#pragma unroll
        for (int j = 0; j < 8; ++j)
            af[k0][j] = (f16)(eps1 * ((float)hv[j] + (float)vv[j]) + (float)ag[j]);
    }

    // ---- phase A: z = relu(acc*ZA + ZB) stored /16 in zs cols 0-255 ----
#pragma unroll
    for (int qt = 0; qt < 4; ++qt) {
        f32x4 acc[4] = {};
#pragma unroll
        for (int k0 = 0; k0 < 4; ++k0) {
            int ko = k0 * 32 + lg * 8;
#pragma unroll
            for (int fc = 0; fc < 4; ++fc) {
                int col = qt * 64 + fc * 16 + lr;
                f16x8 bf = *(const f16x8*)(W1t + (size_t)col * 128 + ko);
                acc[fc] = __builtin_amdgcn_mfma_f32_16x16x32_f16(af[k0], bf, acc[fc], 0, 0, 0);
            }
        }
#pragma unroll
        for (int fc = 0; fc < 4; ++fc) {
            int col = qt * 64 + fc * 16 + lr;
            float za = ZA[col], zb = ZB[col];
#pragma unroll
            for (int reg = 0; reg < 4; ++reg) {
                float zv = fmaxf(acc[fc][reg] * za + zb, 0.f);
                zs[rl[reg]][(((col >> 3) ^ (rl[reg] & 7)) << 3) | (col & 7)] = f2h(zv);
            }
        }
    }

    // ---- phase B: h' = acc*16 + b2 -> global h16 + zs cols 0-127 (/16) ----
    {
        f32x4 acc2[8] = {};
#pragma unroll
        for (int k0 = 0; k0 < 8; ++k0) {
            int ko = k0 * 32 + lg * 8;
            f16x8 az = *(const f16x8*)&zs[myrow][(((k0 * 4 + lg) ^ lr7)) << 3];
#pragma unroll
            for (int ofc = 0; ofc < 8; ++ofc) {
                int col = (ofc >> 2) * 64 + (ofc & 3) * 16 + lr;
                f16x8 bf = *(const f16x8*)(W2t + (size_t)col * 256 + ko);
                acc2[ofc] = __builtin_amdgcn_mfma_f32_16x16x32_f16(az, bf, acc2[ofc], 0, 0, 0);
            }
        }
#pragma unroll
        for (int ofc = 0; ofc < 8; ++ofc) {
            int col = (ofc >> 2) * 64 + (ofc & 3) * 16 + lr;   // 0..127
            float bb = b2[col];
#pragma unroll
            for (int reg = 0; reg < 4; ++reg) {
                float hv = acc2[ofc][reg] * 16.f + bb;
                ushort hq = f2h(hv * 0.0625f);
                h16[(size_t)(r0 + rl[reg]) * HH + col] = hq;
                zs[rl[reg]][(((col >> 3) ^ (rl[reg] & 7)) << 3) | (col & 7)] = hq;
            }
        }
    }

    // ---- phase C: t = relu(acc*TA + vnW' + TB) -> zs cols 128-255; pool per pair ----
    for (int pr = 0; pr < 2; ++pr) {
#pragma unroll
        for (int sub = 0; sub < 2; ++sub) {
            int qt = pr * 2 + sub;
            f32x4 acc3[4] = {};
#pragma unroll
            for (int k0 = 0; k0 < 4; ++k0) {
                int ko = k0 * 32 + lg * 8;
                f16x8 ah = *(const f16x8*)&zs[myrow][(((k0 * 4 + lg) ^ lr7)) << 3];
#pragma unroll
                for (int fc = 0; fc < 4; ++fc) {
                    int col = qt * 64 + fc * 16 + lr;
                    f16x8 bf = *(const f16x8*)(W3t + (size_t)col * 128 + ko);
                    acc3[fc] = __builtin_amdgcn_mfma_f32_16x16x32_f16(ah, bf, acc3[fc], 0, 0, 0);
                }
            }
#pragma unroll
            for (int fc = 0; fc < 4; ++fc) {
                int colg = qt * 64 + fc * 16 + lr;             // global col 0..255
                int colL = 128 + sub * 64 + fc * 16 + lr;      // LDS col 128..255
                float ta = TA[colg], tb = TB[colg];
#pragma unroll
                for (int reg = 0; reg < 4; ++reg) {
                    float tv = fmaxf(acc3[fc][reg] * ta + vnW[(size_t)ggs[reg] * 256 + colg] + tb, 0.f);
                    zs[rl[reg]][(((colL >> 3) ^ (rl[reg] & 7)) << 3) | (colL & 7)] = f2h(tv);
                }
            }
        }
        __syncthreads();
        {   // pool 128 global cols (pr*128 + c): 2 threads/col, 32 rows each
            int c = tid & 127, half = tid >> 7;
            int gcol = pr * 128 + c;
            int colL = 128 + c;
            float s = 0.f;
            int cur = batch[r0 + half * 32];
            for (int r = half * 32; r < half * 32 + 32; ++r) {
                int gg = batch[r0 + r];
                if (gg != cur) {
                    atomicAdd(&pooled[(size_t)cur * 256 + gcol], s);
                    s = 0.f; cur = gg;
                }
                s += h2f(zs[r][(((colL >> 3) ^ (r & 7)) << 3) | (colL & 7)]);
            }
            atomicAdd(&pooled[(size_t)cur * 256 + gcol], s);
        }
        __syncthreads();
    }
}

// ---------------- small f32 GEMM (GEMM3a, GEMM4) ----------------
enum { E_BIAS = 0, E_BNRELU = 1 };
template <int EMODE>
__global__ void __launch_bounds__(256)
gemm_k(const void* __restrict__ Av, const float* __restrict__ B,
       const float* __restrict__ bias,
       const float* __restrict__ g_, const float* __restrict__ b_,
       const float* __restrict__ m_, const float* __restrict__ v_,
       const float* __restrict__ scp,
       void* __restrict__ outv, int K, int Nc) {
    __shared__ float As[64][33];
    __shared__ float Bs[32][64];
    const int tid = threadIdx.x;
    const int row0 = blockIdx.x * 64;
    const int col0 = blockIdx.y * 64;
    float acc[4][4] = {};
    const int tx = tid & 15, ty = tid >> 4;
    for (int k0 = 0; k0 < K; k0 += 32) {
#pragma unroll
        for (int p = 0; p < 2; ++p) {
            int idx = p * 256 + tid;
            {
                int r = idx >> 3, c = (idx & 7) << 2;
                size_t aoff = (size_t)(row0 + r) * K + k0 + c;
                float4 va = *(const float4*)((const float*)Av + aoff);
                As[r][c + 0] = va.x; As[r][c + 1] = va.y;
                As[r][c + 2] = va.z; As[r][c + 3] = va.w;
            }
            {
                int kr = idx >> 4, cc = (idx & 15) << 2;
                *(float4*)&Bs[kr][cc] =
                    *(const float4*)(B + (size_t)(k0 + kr) * Nc + col0 + cc);
            }
        }
        __syncthreads();
#pragma unroll
        for (int k = 0; k < 32; ++k) {
            float4 bv = *(const float4*)&Bs[k][tx << 2];
            float a0 = As[ty * 4 + 0][k];
            float a1 = As[ty * 4 + 1][k];
            float a2 = As[ty * 4 + 2][k];
            float a3 = As[ty * 4 + 3][k];
            acc[0][0] += a0 * bv.x; acc[0][1] += a0 * bv.y; acc[0][2] += a0 * bv.z; acc[0][3] += a0 * bv.w;
            acc[1][0] += a1 * bv.x; acc[1][1] += a1 * bv.y; acc[1][2] += a1 * bv.z; acc[1][3] += a1 * bv.w;
            acc[2][0] += a2 * bv.x; acc[2][1] += a2 * bv.y; acc[2][2] += a2 * bv.z; acc[2][3] += a2 * bv.w;
            acc[3][0] += a3 * bv.x; acc[3][1] += a3 * bv.y; acc[3][2] += a3 * bv.z; acc[3][3] += a3 * bv.w;
        }
        __syncthreads();
    }
#pragma unroll
    for (int j = 0; j < 4; ++j) {
        int gr = row0 + ty * 4 + j;
        float vals[4];
#pragma unroll
        for (int lx = 0; lx < 4; ++lx) {
            int gc = col0 + (tx << 2) + lx;
            float val = acc[j][lx];
            if (EMODE == E_BIAS) {
                float v = val + bias[gc];
                if (scp) v *= scp[gc];
                vals[lx] = v;
            } else {
                float y = val + bias[gc];
                float s = g_[gc] * rsqrtf(v_[gc] + 1e-5f);
                y = (y - m_[gc]) * s + b_[gc];
                vals[lx] = fmaxf(y, 0.f);
            }
        }
        *(float4*)((float*)outv + (size_t)gr * Nc + col0 + (tx << 2)) =
            make_float4(vals[0], vals[1], vals[2], vals[3]);
    }
}

// ---------------- final head ----------------
__global__ void k_final(const float* __restrict__ vn, const float* __restrict__ pW1,
                        const float* __restrict__ pb1, const float* __restrict__ pW2,
                        const float* __restrict__ pb2, float* __restrict__ out) {
    int g = blockIdx.x;
    int j = threadIdx.x;
    __shared__ float vrow[HH];
    __shared__ float red[HH];
    vrow[j] = vn[(size_t)g * HH + j];
    __syncthreads();
    float acc = pb1[j];
    for (int k = 0; k < HH; ++k) acc = fmaf(vrow[k], pW1[k * HH + j], acc);
    red[j] = fmaxf(acc, 0.f) * pW2[j];
    __syncthreads();
    for (int s = 64; s > 0; s >>= 1) {
        if (j < s) red[j] += red[j + s];
        __syncthreads();
    }
    if (j == 0) out[g] = fminf(fmaxf(red[0] + pb2[0], 0.f), 50.f);
}

extern "C" void kernel_launch(void* const* d_in, const int* in_sizes, int n_in,
                              void* d_out, int out_size, void* d_ws, size_t ws_size,
                              hipStream_t stream) {
    const int*   x        = (const int*)  d_in[0];
    const int*   ei       = (const int*)  d_in[1];
    const int*   ea       = (const int*)  d_in[2];
    const int*   batch    = (const int*)  d_in[3];
    const float* atom_emb = (const float*)d_in[4];
    const float* vn_emb   = (const float*)d_in[5];
    const float* bond_emb = (const float*)d_in[6];
    const float* conv_eps = (const float*)d_in[7];
    const float* conv_W1  = (const float*)d_in[8];
    const float* conv_b1  = (const float*)d_in[9];
    const float* cbn_g    = (const float*)d_in[10];
    const float* cbn_b    = (const float*)d_in[11];
    const float* cbn_m    = (const float*)d_in[12];
    const float* cbn_v    = (const float*)d_in[13];
    const float* conv_W2  = (const float*)d_in[14];
    const float* conv_b2  = (const float*)d_in[15];
    const float* vn1_W    = (const float*)d_in[16];
    const float* vn1_b    = (const float*)d_in[17];
    const float* vn1_g    = (const float*)d_in[18];
    const float* vn1_be   = (const float*)d_in[19];
    const float* vn1_m    = (const float*)d_in[20];
    const float* vn1_v    = (const float*)d_in[21];
    const float* vn2_W    = (const float*)d_in[22];
    const float* vn2_b    = (const float*)d_in[23];
    const float* vn2_g    = (const float*)d_in[24];
    const float* vn2_be   = (const float*)d_in[25];
    const float* vn2_m    = (const float*)d_in[26];
    const float* vn2_v    = (const float*)d_in[27];
    const float* pW1      = (const float*)d_in[28];
    const float* pb1      = (const float*)d_in[29];
    const float* pW2      = (const float*)d_in[30];
    const float* pb2      = (const float*)d_in[31];

    // ---- workspace layout (~165 MB) ----
    char* base = (char*)d_ws;
    ushort*   h16    = (ushort*)base;                                 // NN*HH fp16 (state/16)
    ushort*   agg    = h16 + (size_t)NN * HH;                         // NN*HH fp16
    unsigned* packed = (unsigned*)(agg + (size_t)NN * HH);            // EE u32
    int*      rowptr = (int*)(packed + EE);                           // NN+4
    int*      fill   = rowptr + NN + 4;                               // NN
    float*    ctab   = (float*)(fill + NN);                           // 512*HH f32
    int*      sums   = (int*)(ctab + 512 * HH);                       // 256
    ushort*   W1t    = (ushort*)(sums + 256);                         // 256*128
    ushort*   W2t    = W1t + 256 * 128;                               // 128*256
    ushort*   W3t    = W2t + 128 * 256;                               // 256*128
    float*    ZA     = (float*)(W3t + 256 * 128);                     // 256
    float*    ZB     = ZA + 256;
    float*    TA     = ZB + 256;
    float*    TB     = TA + 256;
    float*    S3     = TB + 256;
    float*    vn     = S3 + 256;                                      // GG*HH f32
    ushort*   vn16   = (ushort*)(vn + (size_t)GG * HH);               // GG*HH fp16
    float*    vnW    = (float*)(vn16 + (size_t)GG * HH);              // GG*256
    float*    pooled = vnW + (size_t)GG * 256;                        // GG*256
    float*    out    = (float*)d_out;

    // ---- setup ----
    k_zero<<<256, 256, 0, stream>>>((float*)fill);
    k_hist<<<EE / 256, 256, 0, stream>>>(ei, fill);
    k_scan1<<<256, 256, 0, stream>>>(fill, rowptr, sums);
    k_scan2<<<1, 256, 0, stream>>>(sums);
    k_scan3<<<256, 256, 0, stream>>>(rowptr, sums, fill);
    k_scatter<<<EE / 256, 256, 0, stream>>>(ei, ea, fill, packed);
    k_atom<<<NN * 32 / 256, 256, 0, stream>>>(x, atom_emb, h16);
    k_init_vn<<<GG * HH / 4 / 256, 256, 0, stream>>>(vn_emb, vn);

    for (int i = 0; i < 4; ++i) {
        k_ctab<<<64, 256, 0, stream>>>(bond_emb + (size_t)i * FBc * VBc * HH, ctab);
        k_prep<<<1, 256, 0, stream>>>(
            conv_b1 + i * 256, cbn_g + i * 256, cbn_b + i * 256,
            cbn_m + i * 256, cbn_v + i * 256,
            vn1_g + i * 256, vn1_be + i * 256, vn1_m + i * 256, vn1_v + i * 256,
            ZA, ZB, TA, TB, S3);
        k_wt<<<128, 256, 0, stream>>>(conv_W1 + (size_t)i * HH * 256, W1t, 7, 256);
        k_wt<<<128, 256, 0, stream>>>(conv_W2 + (size_t)i * 256 * HH, W2t, 8, 128);
        k_wt<<<128, 256, 0, stream>>>(vn1_W + (size_t)i * 256 * 256 + 128 * 256, W3t, 7, 256);
        k_vn16<<<GG * HH / 4 / 256, 256, 0, stream>>>(vn, vn16);

        k_agg<<<NN / 4, 256, 0, stream>>>(h16, vn16, batch, rowptr, packed, ctab, agg);

        // GEMM3a: vnW' = (vn @ vn1_W[:128] + vn1_b) * s3
        {
            dim3 g3(GG / 64, 4);
            gemm_k<E_BIAS><<<g3, 256, 0, stream>>>(
                vn, vn1_W + (size_t)i * 256 * 256, vn1_b + i * 256,
                nullptr, nullptr, nullptr, nullptr, S3, vnW, HH, 256);
        }
        k_zero<<<GG * 256 / 4 / 256, 256, 0, stream>>>(pooled);

        // mega-kernel v3 (register fragments, 32 KB LDS)
        k_conv<<<NN / 64, 256, 0, stream>>>(
            h16, agg, W1t, W2t, W3t, batch, vn16, vnW, conv_eps + i,
            ZA, ZB, conv_b2 + i * HH, TA, TB, pooled);

        // GEMM4: vn = relu(bn(pooled @ vn2_W + vn2_b))
        {
            dim3 g4(GG / 64, 2);
            gemm_k<E_BNRELU><<<g4, 256, 0, stream>>>(
                pooled, vn2_W + (size_t)i * 256 * HH, vn2_b + i * HH,
                vn2_g + i * HH, vn2_be + i * HH, vn2_m + i * HH, vn2_v + i * HH,
                nullptr, vn, 256, HH);
        }
    }
    k_final<<<GG, 128, 0, stream>>>(vn, pW1, pb1, pW2, pb2, out);
}

// Round 13
// 1664.038 us; speedup vs baseline: 1.6480x; 1.6480x over previous
//
#include <hip/hip_runtime.h>
#include <hip/hip_fp16.h>

#define NN 262144
#define EE 1048576
#define GG 8192
#define HH 128
#define FBc 3
#define VAc 64
#define VBc 8
#define FAc 9

typedef _Float16 f16;
typedef _Float16 f16x8 __attribute__((ext_vector_type(8)));
typedef float f32x4 __attribute__((ext_vector_type(4)));

__device__ __forceinline__ float h2f(ushort u) {
    __half h; *(ushort*)&h = u; return __half2float(h);
}
__device__ __forceinline__ ushort f2h(float f) {
    __half h = __float2half_rn(f); return *(ushort*)&h;
}
// LDS swizzle: 16B-block XOR within a row
__device__ __forceinline__ int swz(int col, int row) {
    return (((col >> 3) ^ (row & 7)) << 3) | (col & 7);
}

// ---------------- zero fill ----------------
__global__ void k_zero(float* __restrict__ p) {
    size_t i = (size_t)(blockIdx.x * 256 + threadIdx.x) * 4;
    *(float4*)(p + i) = make_float4(0.f, 0.f, 0.f, 0.f);
}

// ---------------- atom encoder: h16 = (sum emb)/16 fp16 ----------------
__global__ void k_atom(const int* __restrict__ x, const float* __restrict__ emb,
                       ushort* __restrict__ h16) {
    int t = blockIdx.x * 256 + threadIdx.x;
    int n = t >> 5, c = (t & 31) << 2;
    if (n >= NN) return;
    float4 a = make_float4(0.f, 0.f, 0.f, 0.f);
#pragma unroll
    for (int f = 0; f < FAc; ++f) {
        int v = x[n * FAc + f];
        float4 e = *(const float4*)(emb + ((size_t)(f * VAc + v)) * HH + c);
        a.x += e.x; a.y += e.y; a.z += e.z; a.w += e.w;
    }
    ushort4 o;
    o.x = f2h(a.x * 0.0625f); o.y = f2h(a.y * 0.0625f);
    o.z = f2h(a.z * 0.0625f); o.w = f2h(a.w * 0.0625f);
    *(ushort4*)(h16 + (size_t)n * HH + c) = o;
}

// ---------------- vn init ----------------
__global__ void k_init_vn(const float* __restrict__ vn_emb, float* __restrict__ vn) {
    int t = blockIdx.x * 256 + threadIdx.x;
    int g = t >> 5, c = (t & 31) << 2;
    *(float4*)(vn + (size_t)g * HH + c) = *(const float4*)(vn_emb + c);
}

// ---------------- vn16 = vn/16 fp16 ----------------
__global__ void k_vn16(const float* __restrict__ vn, ushort* __restrict__ vn16) {
    int t = blockIdx.x * 256 + threadIdx.x;
    float4 v = *(const float4*)(vn + (size_t)t * 4);
    ushort4 o;
    o.x = f2h(v.x * 0.0625f); o.y = f2h(v.y * 0.0625f);
    o.z = f2h(v.z * 0.0625f); o.w = f2h(v.w * 0.0625f);
    *(ushort4*)(vn16 + (size_t)t * 4) = o;
}

// ================= CSR build =================
__global__ void k_hist(const int* __restrict__ ei, int* __restrict__ deg) {
    int e = blockIdx.x * 256 + threadIdx.x;
    atomicAdd(&deg[ei[EE + e]], 1);
}
__global__ void k_scan1(const int* __restrict__ deg, int* __restrict__ rowptr,
                        int* __restrict__ sums) {
    __shared__ int s[256];
    int base = blockIdx.x * 1024 + threadIdx.x * 4;
    int4 d = *(const int4*)(deg + base);
    int t = d.x + d.y + d.z + d.w;
    s[threadIdx.x] = t;
    __syncthreads();
    for (int off = 1; off < 256; off <<= 1) {
        int v = (threadIdx.x >= off) ? s[threadIdx.x - off] : 0;
        __syncthreads();
        s[threadIdx.x] += v;
        __syncthreads();
    }
    int excl = s[threadIdx.x] - t;
    int4 o; o.x = excl; o.y = excl + d.x; o.z = o.y + d.y; o.w = o.z + d.z;
    *(int4*)(rowptr + base) = o;
    if (threadIdx.x == 255) sums[blockIdx.x] = s[255];
}
__global__ void k_scan2(int* __restrict__ sums) {
    __shared__ int s[256];
    int t = sums[threadIdx.x];
    s[threadIdx.x] = t;
    __syncthreads();
    for (int off = 1; off < 256; off <<= 1) {
        int v = (threadIdx.x >= off) ? s[threadIdx.x - off] : 0;
        __syncthreads();
        s[threadIdx.x] += v;
        __syncthreads();
    }
    sums[threadIdx.x] = s[threadIdx.x] - t;
}
__global__ void k_scan3(int* __restrict__ rowptr, const int* __restrict__ sums,
                        int* __restrict__ fill) {
    int base = blockIdx.x * 1024 + threadIdx.x * 4;
    int add = sums[blockIdx.x];
    int4 r = *(const int4*)(rowptr + base);
    r.x += add; r.y += add; r.z += add; r.w += add;
    *(int4*)(rowptr + base) = r;
    *(int4*)(fill + base) = r;
    if (blockIdx.x == 0 && threadIdx.x == 0) rowptr[NN] = EE;
}
__global__ void k_scatter(const int* __restrict__ ei, const int* __restrict__ ea,
                          int* __restrict__ fill, unsigned* __restrict__ packed) {
    int e = blockIdx.x * 256 + threadIdx.x;
    int dst = ei[EE + e];
    int pos = atomicAdd(&fill[dst], 1);
    unsigned cb = (unsigned)(ea[e * 3 + 0] + ea[e * 3 + 1] * 8 + ea[e * 3 + 2] * 64);
    packed[pos] = (unsigned)ei[e] | (cb << 18);
}

// per-layer bond-combo table
__global__ void k_ctab(const float* __restrict__ bemb, float* __restrict__ ctab) {
    int t = blockIdx.x * 256 + threadIdx.x;
    int cb = t >> 5, c = (t & 31) << 2;
    int a0 = cb & 7, a1 = (cb >> 3) & 7, a2 = cb >> 6;
    float4 b0 = *(const float4*)(bemb + (size_t)(0 * VBc + a0) * HH + c);
    float4 b1 = *(const float4*)(bemb + (size_t)(1 * VBc + a1) * HH + c);
    float4 b2 = *(const float4*)(bemb + (size_t)(2 * VBc + a2) * HH + c);
    float4 o = make_float4(b0.x + b1.x + b2.x, b0.y + b1.y + b2.y,
                           b0.z + b1.z + b2.z, b0.w + b1.w + b2.w);
    *(float4*)(ctab + (size_t)cb * HH + c) = o;
}

// per-layer folded BN tables
__global__ void k_prep(const float* __restrict__ b1, const float* __restrict__ g1,
                       const float* __restrict__ be1, const float* __restrict__ m1,
                       const float* __restrict__ v1,
                       const float* __restrict__ g3, const float* __restrict__ be3,
                       const float* __restrict__ m3, const float* __restrict__ v3,
                       float* __restrict__ ZA, float* __restrict__ ZB,
                       float* __restrict__ TA, float* __restrict__ TB,
                       float* __restrict__ S3) {
    int c = threadIdx.x;   // 256
    float s1 = g1[c] * rsqrtf(v1[c] + 1e-5f);
    ZA[c] = s1;
    ZB[c] = ((b1[c] - m1[c]) * s1 + be1[c]) * 0.0625f;
    float s3 = g3[c] * rsqrtf(v3[c] + 1e-5f);
    TA[c] = 16.f * s3;
    TB[c] = be3[c] - m3[c] * s3;
    S3[c] = s3;
}

// weight transpose: W [K][Nsrc] f32 -> Wt [N][K] fp16
__global__ void k_wt(const float* __restrict__ W, ushort* __restrict__ Wt, int lk, int Nsrc) {
    int o = blockIdx.x * 256 + threadIdx.x;
    int K = 1 << lk;
    int c = o >> lk, k = o & (K - 1);
    Wt[o] = f2h(W[(size_t)k * Nsrc + c]);
}

// CSR aggregation: agg[n] = (1/16) sum relu(16*(h16[src]+vn16[batch[src]])+ctab)
__global__ void k_agg(const ushort* __restrict__ h16, const ushort* __restrict__ vn16,
                      const int* __restrict__ batch,
                      const int* __restrict__ rowptr, const unsigned* __restrict__ packed,
                      const float* __restrict__ ctab, ushort* __restrict__ agg) {
    int n = blockIdx.x * 4 + (threadIdx.x >> 6);
    int lane = threadIdx.x & 63;
    int co = lane * 2;
    int beg = rowptr[n], end = rowptr[n + 1];
    float a0 = 0.f, a1 = 0.f;
    int i = beg;
    for (; i + 1 < end; i += 2) {
        unsigned p0 = packed[i], p1 = packed[i + 1];
        int s0 = p0 & 0x3FFFF, s1 = p1 & 0x3FFFF;
        int c0 = p0 >> 18, c1 = p1 >> 18;
        ushort2 u0 = *(const ushort2*)(h16 + (size_t)s0 * HH + co);
        ushort2 u1 = *(const ushort2*)(h16 + (size_t)s1 * HH + co);
        ushort2 w0 = *(const ushort2*)(vn16 + (size_t)batch[s0] * HH + co);
        ushort2 w1 = *(const ushort2*)(vn16 + (size_t)batch[s1] * HH + co);
        float2 t0 = *(const float2*)(ctab + (size_t)c0 * HH + co);
        float2 t1 = *(const float2*)(ctab + (size_t)c1 * HH + co);
        a0 += fmaxf(16.f * (h2f(u0.x) + h2f(w0.x)) + t0.x, 0.f)
            + fmaxf(16.f * (h2f(u1.x) + h2f(w1.x)) + t1.x, 0.f);
        a1 += fmaxf(16.f * (h2f(u0.y) + h2f(w0.y)) + t0.y, 0.f)
            + fmaxf(16.f * (h2f(u1.y) + h2f(w1.y)) + t1.y, 0.f);
    }
    if (i < end) {
        unsigned p = packed[i];
        int src = p & 0x3FFFF, cb = p >> 18;
        ushort2 u = *(const ushort2*)(h16 + (size_t)src * HH + co);
        ushort2 wv = *(const ushort2*)(vn16 + (size_t)batch[src] * HH + co);
        float2 ct = *(const float2*)(ctab + (size_t)cb * HH + co);
        a0 += fmaxf(16.f * (h2f(u.x) + h2f(wv.x)) + ct.x, 0.f);
        a1 += fmaxf(16.f * (h2f(u.y) + h2f(wv.y)) + ct.y, 0.f);
    }
    ushort2 o; o.x = f2h(a0 * 0.0625f); o.y = f2h(a1 * 0.0625f);
    *(ushort2*)(agg + (size_t)n * HH + co) = o;
}

// ============== mega-kernel v4: 64-row tile, LDS weights in 2-half stages,
// register prefetch of next weight tile, 6 staging barriers total ==============
__global__ void __launch_bounds__(256, 2)
k_conv(ushort* __restrict__ h16, const ushort* __restrict__ agg,
       const ushort* __restrict__ W1t, const ushort* __restrict__ W2t,
       const ushort* __restrict__ W3t,
       const int* __restrict__ batch, const ushort* __restrict__ vn16,
       const float* __restrict__ vnW,
       const float* __restrict__ eps_ptr,
       const float* __restrict__ ZA, const float* __restrict__ ZB,
       const float* __restrict__ b2,
       const float* __restrict__ TA, const float* __restrict__ TB,
       float* __restrict__ pooled) {
    __shared__ ushort As[64][128];     // A/16, then h'/16   16 KB
    __shared__ ushort zs[64][256];     // z/16, then t       32 KB
    __shared__ ushort Wb[128][128];    // weight tile        32 KB   (total 80 KB)
    ushort(*Wb2)[256] = (ushort(*)[256]) & Wb[0][0];   // [64][256] view for W2
    const int tid = threadIdx.x;
    const int r0 = blockIdx.x * 64;
    const int w = tid >> 6, l = tid & 63, lr = l & 15, lg = l >> 4, lr7 = lr & 7;
    const float eps1 = 1.f + eps_ptr[0];
    const int myrow = w * 16 + lr;
    int rl[4], ggs[4];
#pragma unroll
    for (int reg = 0; reg < 4; ++reg) {
        rl[reg] = w * 16 + lg * 4 + reg;
        ggs[reg] = batch[r0 + rl[reg]];
    }

    // ---- prefetch W1 half 0 into registers ----
    f16x8 wreg[8];
    {
        int c = tid >> 1, q = tid & 1;
        const ushort* s = W1t + (size_t)c * 128 + q * 64;
#pragma unroll
        for (int j = 0; j < 8; ++j) wreg[j] = *(const f16x8*)(s + j * 8);
    }

    // ---- stage A (wave-local rows): A/16 = eps1*(h16 + vn16) + agg16 ----
    {
        int row = tid >> 2, q = tid & 3, r7 = row & 7;
        int gg = batch[r0 + row];
        const ushort* hp = h16 + (size_t)(r0 + row) * HH;
        const ushort* vp = vn16 + (size_t)gg * HH;
        const ushort* ap = agg + (size_t)(r0 + row) * HH;
#pragma unroll
        for (int j4 = 0; j4 < 4; ++j4) {
            int c0 = q * 32 + j4 * 8;
            f16x8 hv = *(const f16x8*)(hp + c0);
            f16x8 vg = *(const f16x8*)(vp + c0);
            f16x8 ag = *(const f16x8*)(ap + c0);
            f16x8 o;
#pragma unroll
            for (int j = 0; j < 8; ++j)
                o[j] = (f16)(eps1 * ((float)hv[j] + (float)vg[j]) + (float)ag[j]);
            *(f16x8*)&As[row][((c0 >> 3) ^ r7) << 3] = o;
        }
    }

    // ---- phase A: z = relu(acc*ZA + ZB)/16 -> zs; W1 in 2 halves ----
    for (int ch = 0; ch < 2; ++ch) {
        __syncthreads();
        {   // write prefetched W1 half [128 cols][128 K]
            int c = tid >> 1, q = tid & 1, c7 = c & 7;
#pragma unroll
            for (int j = 0; j < 8; ++j)
                *(f16x8*)&Wb[c][((q * 8 + j) ^ c7) << 3] = wreg[j];
        }
        __syncthreads();
        // prefetch next tile (W1 half1, then W2 half0)
        if (ch == 0) {
            int c = tid >> 1, q = tid & 1;
            const ushort* s = W1t + (size_t)(128 + c) * 128 + q * 64;
#pragma unroll
            for (int j = 0; j < 8; ++j) wreg[j] = *(const f16x8*)(s + j * 8);
        } else {
            int c = tid >> 2, q = tid & 3;
            const ushort* s = W2t + (size_t)c * 256 + q * 64;
#pragma unroll
            for (int j = 0; j < 8; ++j) wreg[j] = *(const f16x8*)(s + j * 8);
        }
        f32x4 acc[8] = {};
#pragma unroll
        for (int k0 = 0; k0 < 4; ++k0) {
            int sb = ((k0 * 4 + lg) ^ lr7) << 3;
            f16x8 af = *(const f16x8*)&As[myrow][sb];
#pragma unroll
            for (int fc = 0; fc < 8; ++fc) {
                f16x8 bf = *(const f16x8*)&Wb[fc * 16 + lr][sb];
                acc[fc] = __builtin_amdgcn_mfma_f32_16x16x32_f16(af, bf, acc[fc], 0, 0, 0);
            }
        }
#pragma unroll
        for (int fc = 0; fc < 8; ++fc) {
            int col = ch * 128 + fc * 16 + lr;
            float za = ZA[col], zb = ZB[col];
#pragma unroll
            for (int reg = 0; reg < 4; ++reg) {
                float zv = fmaxf(acc[fc][reg] * za + zb, 0.f);
                zs[rl[reg]][swz(col, rl[reg])] = f2h(zv);
            }
        }
    }

    // ---- phase B: h' = acc*16 + b2 -> global h16 + As; W2 in 2 halves ----
    for (int ch2 = 0; ch2 < 2; ++ch2) {
        __syncthreads();
        {   // write prefetched W2 half [64 outcols][256 K]
            int c = tid >> 2, q = tid & 3, c7 = c & 7;
#pragma unroll
            for (int j = 0; j < 8; ++j)
                *(f16x8*)&Wb2[c][((q * 8 + j) ^ c7) << 3] = wreg[j];
        }
        __syncthreads();
        // prefetch next (W2 half1, then W3 half0)
        if (ch2 == 0) {
            int c = tid >> 2, q = tid & 3;
            const ushort* s = W2t + (size_t)(64 + c) * 256 + q * 64;
#pragma unroll
            for (int j = 0; j < 8; ++j) wreg[j] = *(const f16x8*)(s + j * 8);
        } else {
            int c = tid >> 1, q = tid & 1;
            const ushort* s = W3t + (size_t)c * 128 + q * 64;
#pragma unroll
            for (int j = 0; j < 8; ++j) wreg[j] = *(const f16x8*)(s + j * 8);
        }
        f32x4 acc[4] = {};
#pragma unroll
        for (int k0 = 0; k0 < 8; ++k0) {
            int sb = ((k0 * 4 + lg) ^ lr7) << 3;
            f16x8 az = *(const f16x8*)&zs[myrow][sb];
#pragma unroll
            for (int fc = 0; fc < 4; ++fc) {
                f16x8 bf = *(const f16x8*)&Wb2[fc * 16 + lr][sb];
                acc[fc] = __builtin_amdgcn_mfma_f32_16x16x32_f16(az, bf, acc[fc], 0, 0, 0);
            }
        }
#pragma unroll
        for (int fc = 0; fc < 4; ++fc) {
            int col = ch2 * 64 + fc * 16 + lr;
            float bb = b2[col];
#pragma unroll
            for (int reg = 0; reg < 4; ++reg) {
                float hv = acc[fc][reg] * 16.f + bb;
                ushort hq = f2h(hv * 0.0625f);
                h16[(size_t)(r0 + rl[reg]) * HH + col] = hq;
                As[rl[reg]][swz(col, rl[reg])] = hq;
            }
        }
    }

    // ---- phase C: t = relu(acc*TA + vnW' + TB) -> zs (full 256 cols); W3 in 2 halves ----
    for (int ch3 = 0; ch3 < 2; ++ch3) {
        __syncthreads();
        {   // write prefetched W3 half [128 cols][128 K]
            int c = tid >> 1, q = tid & 1, c7 = c & 7;
#pragma unroll
            for (int j = 0; j < 8; ++j)
                *(f16x8*)&Wb[c][((q * 8 + j) ^ c7) << 3] = wreg[j];
        }
        __syncthreads();
        if (ch3 == 0) {   // prefetch W3 half1
            int c = tid >> 1, q = tid & 1;
            const ushort* s = W3t + (size_t)(128 + c) * 128 + q * 64;
#pragma unroll
            for (int j = 0; j < 8; ++j) wreg[j] = *(const f16x8*)(s + j * 8);
        }
        f32x4 acc[8] = {};
#pragma unroll
        for (int k0 = 0; k0 < 4; ++k0) {
            int sb = ((k0 * 4 + lg) ^ lr7) << 3;
            f16x8 ah = *(const f16x8*)&As[myrow][sb];
#pragma unroll
            for (int fc = 0; fc < 8; ++fc) {
                f16x8 bf = *(const f16x8*)&Wb[fc * 16 + lr][sb];
                acc[fc] = __builtin_amdgcn_mfma_f32_16x16x32_f16(ah, bf, acc[fc], 0, 0, 0);
            }
        }
#pragma unroll
        for (int fc = 0; fc < 8; ++fc) {
            int colg = ch3 * 128 + fc * 16 + lr;
            float ta = TA[colg], tb = TB[colg];
#pragma unroll
            for (int reg = 0; reg < 4; ++reg) {
                float tv = fmaxf(acc[fc][reg] * ta + vnW[(size_t)ggs[reg] * 256 + colg] + tb, 0.f);
                zs[rl[reg]][swz(colg, rl[reg])] = f2h(tv);
            }
        }
    }
    __syncthreads();
    // ---- pool: 256 threads, one col each, run-length over 64 sorted rows ----
    {
        int col = tid;
        float s = 0.f;
        int cur = batch[r0];
        for (int r = 0; r < 64; ++r) {
            int gg = batch[r0 + r];
            if (gg != cur) {
                atomicAdd(&pooled[(size_t)cur * 256 + col], s);
                s = 0.f; cur = gg;
            }
            s += h2f(zs[r][swz(col, r)]);
        }
        atomicAdd(&pooled[(size_t)cur * 256 + col], s);
    }
}

// ---------------- small f32 GEMM (GEMM3a, GEMM4) ----------------
enum { E_BIAS = 0, E_BNRELU = 1 };
template <int EMODE>
__global__ void __launch_bounds__(256)
gemm_k(const void* __restrict__ Av, const float* __restrict__ B,
       const float* __restrict__ bias,
       const float* __restrict__ g_, const float* __restrict__ b_,
       const float* __restrict__ m_, const float* __restrict__ v_,
       const float* __restrict__ scp,
       void* __restrict__ outv, int K, int Nc) {
    __shared__ float As[64][33];
    __shared__ float Bs[32][64];
    const int tid = threadIdx.x;
    const int row0 = blockIdx.x * 64;
    const int col0 = blockIdx.y * 64;
    float acc[4][4] = {};
    const int tx = tid & 15, ty = tid >> 4;
    for (int k0 = 0; k0 < K; k0 += 32) {
#pragma unroll
        for (int p = 0; p < 2; ++p) {
            int idx = p * 256 + tid;
            {
                int r = idx >> 3, c = (idx & 7) << 2;
                size_t aoff = (size_t)(row0 + r) * K + k0 + c;
                float4 va = *(const float4*)((const float*)Av + aoff);
                As[r][c + 0] = va.x; As[r][c + 1] = va.y;
                As[r][c + 2] = va.z; As[r][c + 3] = va.w;
            }
            {
                int kr = idx >> 4, cc = (idx & 15) << 2;
                *(float4*)&Bs[kr][cc] =
                    *(const float4*)(B + (size_t)(k0 + kr) * Nc + col0 + cc);
            }
        }
        __syncthreads();
#pragma unroll
        for (int k = 0; k < 32; ++k) {
            float4 bv = *(const float4*)&Bs[k][tx << 2];
            float a0 = As[ty * 4 + 0][k];
            float a1 = As[ty * 4 + 1][k];
            float a2 = As[ty * 4 + 2][k];
            float a3 = As[ty * 4 + 3][k];
            acc[0][0] += a0 * bv.x; acc[0][1] += a0 * bv.y; acc[0][2] += a0 * bv.z; acc[0][3] += a0 * bv.w;
            acc[1][0] += a1 * bv.x; acc[1][1] += a1 * bv.y; acc[1][2] += a1 * bv.z; acc[1][3] += a1 * bv.w;
            acc[2][0] += a2 * bv.x; acc[2][1] += a2 * bv.y; acc[2][2] += a2 * bv.z; acc[2][3] += a2 * bv.w;
            acc[3][0] += a3 * bv.x; acc[3][1] += a3 * bv.y; acc[3][2] += a3 * bv.z; acc[3][3] += a3 * bv.w;
        }
        __syncthreads();
    }
#pragma unroll
    for (int j = 0; j < 4; ++j) {
        int gr = row0 + ty * 4 + j;
        float vals[4];
#pragma unroll
        for (int lx = 0; lx < 4; ++lx) {
            int gc = col0 + (tx << 2) + lx;
            float val = acc[j][lx];
            if (EMODE == E_BIAS) {
                float v = val + bias[gc];
                if (scp) v *= scp[gc];
                vals[lx] = v;
            } else {
                float y = val + bias[gc];
                float s = g_[gc] * rsqrtf(v_[gc] + 1e-5f);
                y = (y - m_[gc]) * s + b_[gc];
                vals[lx] = fmaxf(y, 0.f);
            }
        }
        *(float4*)((float*)outv + (size_t)gr * Nc + col0 + (tx << 2)) =
            make_float4(vals[0], vals[1], vals[2], vals[3]);
    }
}

// ---------------- final head ----------------
__global__ void k_final(const float* __restrict__ vn, const float* __restrict__ pW1,
                        const float* __restrict__ pb1, const float* __restrict__ pW2,
                        const float* __restrict__ pb2, float* __restrict__ out) {
    int g = blockIdx.x;
    int j = threadIdx.x;
    __shared__ float vrow[HH];
    __shared__ float red[HH];
    vrow[j] = vn[(size_t)g * HH + j];
    __syncthreads();
    float acc = pb1[j];
    for (int k = 0; k < HH; ++k) acc = fmaf(vrow[k], pW1[k * HH + j], acc);
    red[j] = fmaxf(acc, 0.f) * pW2[j];
    __syncthreads();
    for (int s = 64; s > 0; s >>= 1) {
        if (j < s) red[j] += red[j + s];
        __syncthreads();
    }
    if (j == 0) out[g] = fminf(fmaxf(red[0] + pb2[0], 0.f), 50.f);
}

extern "C" void kernel_launch(void* const* d_in, const int* in_sizes, int n_in,
                              void* d_out, int out_size, void* d_ws, size_t ws_size,
                              hipStream_t stream) {
    const int*   x        = (const int*)  d_in[0];
    const int*   ei       = (const int*)  d_in[1];
    const int*   ea       = (const int*)  d_in[2];
    const int*   batch    = (const int*)  d_in[3];
    const float* atom_emb = (const float*)d_in[4];
    const float* vn_emb   = (const float*)d_in[5];
    const float* bond_emb = (const float*)d_in[6];
    const float* conv_eps = (const float*)d_in[7];
    const float* conv_W1  = (const float*)d_in[8];
    const float* conv_b1  = (const float*)d_in[9];
    const float* cbn_g    = (const float*)d_in[10];
    const float* cbn_b    = (const float*)d_in[11];
    const float* cbn_m    = (const float*)d_in[12];
    const float* cbn_v    = (const float*)d_in[13];
    const float* conv_W2  = (const float*)d_in[14];
    const float* conv_b2  = (const float*)d_in[15];
    const float* vn1_W    = (const float*)d_in[16];
    const float* vn1_b    = (const float*)d_in[17];
    const float* vn1_g    = (const float*)d_in[18];
    const float* vn1_be   = (const float*)d_in[19];
    const float* vn1_m    = (const float*)d_in[20];
    const float* vn1_v    = (const float*)d_in[21];
    const float* vn2_W    = (const float*)d_in[22];
    const float* vn2_b    = (const float*)d_in[23];
    const float* vn2_g    = (const float*)d_in[24];
    const float* vn2_be   = (const float*)d_in[25];
    const float* vn2_m    = (const float*)d_in[26];
    const float* vn2_v    = (const float*)d_in[27];
    const float* pW1      = (const float*)d_in[28];
    const float* pb1      = (const float*)d_in[29];
    const float* pW2      = (const float*)d_in[30];
    const float* pb2      = (const float*)d_in[31];

    // ---- workspace layout (~165 MB) ----
    char* base = (char*)d_ws;
    ushort*   h16    = (ushort*)base;                                 // NN*HH fp16 (state/16)
    ushort*   agg    = h16 + (size_t)NN * HH;                         // NN*HH fp16
    unsigned* packed = (unsigned*)(agg + (size_t)NN * HH);            // EE u32
    int*      rowptr = (int*)(packed + EE);                           // NN+4
    int*      fill   = rowptr + NN + 4;                               // NN
    float*    ctab   = (float*)(fill + NN);                           // 512*HH f32
    int*      sums   = (int*)(ctab + 512 * HH);                       // 256
    ushort*   W1t    = (ushort*)(sums + 256);                         // 256*128
    ushort*   W2t    = W1t + 256 * 128;                               // 128*256
    ushort*   W3t    = W2t + 128 * 256;                               // 256*128
    float*    ZA     = (float*)(W3t + 256 * 128);                     // 256
    float*    ZB     = ZA + 256;
    float*    TA     = ZB + 256;
    float*    TB     = TA + 256;
    float*    S3     = TB + 256;
    float*    vn     = S3 + 256;                                      // GG*HH f32
    ushort*   vn16   = (ushort*)(vn + (size_t)GG * HH);               // GG*HH fp16
    float*    vnW    = (float*)(vn16 + (size_t)GG * HH);              // GG*256
    float*    pooled = vnW + (size_t)GG * 256;                        // GG*256
    float*    out    = (float*)d_out;

    // ---- setup ----
    k_zero<<<256, 256, 0, stream>>>((float*)fill);
    k_hist<<<EE / 256, 256, 0, stream>>>(ei, fill);
    k_scan1<<<256, 256, 0, stream>>>(fill, rowptr, sums);
    k_scan2<<<1, 256, 0, stream>>>(sums);
    k_scan3<<<256, 256, 0, stream>>>(rowptr, sums, fill);
    k_scatter<<<EE / 256, 256, 0, stream>>>(ei, ea, fill, packed);
    k_atom<<<NN * 32 / 256, 256, 0, stream>>>(x, atom_emb, h16);
    k_init_vn<<<GG * HH / 4 / 256, 256, 0, stream>>>(vn_emb, vn);

    for (int i = 0; i < 4; ++i) {
        k_ctab<<<64, 256, 0, stream>>>(bond_emb + (size_t)i * FBc * VBc * HH, ctab);
        k_prep<<<1, 256, 0, stream>>>(
            conv_b1 + i * 256, cbn_g + i * 256, cbn_b + i * 256,
            cbn_m + i * 256, cbn_v + i * 256,
            vn1_g + i * 256, vn1_be + i * 256, vn1_m + i * 256, vn1_v + i * 256,
            ZA, ZB, TA, TB, S3);
        k_wt<<<128, 256, 0, stream>>>(conv_W1 + (size_t)i * HH * 256, W1t, 7, 256);
        k_wt<<<128, 256, 0, stream>>>(conv_W2 + (size_t)i * 256 * HH, W2t, 8, 128);
        k_wt<<<128, 256, 0, stream>>>(vn1_W + (size_t)i * 256 * 256 + 128 * 256, W3t, 7, 256);
        k_vn16<<<GG * HH / 4 / 256, 256, 0, stream>>>(vn, vn16);

        k_agg<<<NN / 4, 256, 0, stream>>>(h16, vn16, batch, rowptr, packed, ctab, agg);

        // GEMM3a: vnW' = (vn @ vn1_W[:128] + vn1_b) * s3
        {
            dim3 g3(GG / 64, 4);
            gemm_k<E_BIAS><<<g3, 256, 0, stream>>>(
                vn, vn1_W + (size_t)i * 256 * 256, vn1_b + i * 256,
                nullptr, nullptr, nullptr, nullptr, S3, vnW, HH, 256);
        }
        k_zero<<<GG * 256 / 4 / 256, 256, 0, stream>>>(pooled);

        // mega-kernel v4
        k_conv<<<NN / 64, 256, 0, stream>>>(
            h16, agg, W1t, W2t, W3t, batch, vn16, vnW, conv_eps + i,
            ZA, ZB, conv_b2 + i * HH, TA, TB, pooled);

        // GEMM4: vn = relu(bn(pooled @ vn2_W + vn2_b))
        {
            dim3 g4(GG / 64, 2);
            gemm_k<E_BNRELU><<<g4, 256, 0, stream>>>(
                pooled, vn2_W + (size_t)i * 256 * HH, vn2_b + i * HH,
                vn2_g + i * HH, vn2_be + i * HH, vn2_m + i * HH, vn2_v + i * HH,
                nullptr, vn, 256, HH);
        }
    }
    k_final<<<GG, 128, 0, stream>>>(vn, pW1, pb1, pW2, pb2, out);
}

// Round 14
// 1546.941 us; speedup vs baseline: 1.7727x; 1.0757x over previous
//
#include <hip/hip_runtime.h>
#include <hip/hip_fp16.h>

#define NN 262144
#define EE 1048576
#define GG 8192
#define HH 128
#define FBc 3
#define VAc 64
#define VBc 8
#define FAc 9

typedef _Float16 f16;
typedef _Float16 f16x8 __attribute__((ext_vector_type(8)));
typedef float f32x4 __attribute__((ext_vector_type(4)));

__device__ __forceinline__ float h2f(ushort u) {
    __half h; *(ushort*)&h = u; return __half2float(h);
}
__device__ __forceinline__ ushort f2h(float f) {
    __half h = __float2half_rn(f); return *(ushort*)&h;
}
// LDS swizzle: 16B-block XOR within a row
__device__ __forceinline__ int swz(int col, int row) {
    return (((col >> 3) ^ (row & 7)) << 3) | (col & 7);
}

// ---------------- zero fill ----------------
__global__ void k_zero(float* __restrict__ p) {
    size_t i = (size_t)(blockIdx.x * 256 + threadIdx.x) * 4;
    *(float4*)(p + i) = make_float4(0.f, 0.f, 0.f, 0.f);
}

// ---------------- atom encoder: h16 = (sum emb)/16 fp16 ----------------
__global__ void k_atom(const int* __restrict__ x, const float* __restrict__ emb,
                       ushort* __restrict__ h16) {
    int t = blockIdx.x * 256 + threadIdx.x;
    int n = t >> 5, c = (t & 31) << 2;
    if (n >= NN) return;
    float4 a = make_float4(0.f, 0.f, 0.f, 0.f);
#pragma unroll
    for (int f = 0; f < FAc; ++f) {
        int v = x[n * FAc + f];
        float4 e = *(const float4*)(emb + ((size_t)(f * VAc + v)) * HH + c);
        a.x += e.x; a.y += e.y; a.z += e.z; a.w += e.w;
    }
    ushort4 o;
    o.x = f2h(a.x * 0.0625f); o.y = f2h(a.y * 0.0625f);
    o.z = f2h(a.z * 0.0625f); o.w = f2h(a.w * 0.0625f);
    *(ushort4*)(h16 + (size_t)n * HH + c) = o;
}

// ---------------- vn init ----------------
__global__ void k_init_vn(const float* __restrict__ vn_emb, float* __restrict__ vn) {
    int t = blockIdx.x * 256 + threadIdx.x;
    int g = t >> 5, c = (t & 31) << 2;
    *(float4*)(vn + (size_t)g * HH + c) = *(const float4*)(vn_emb + c);
}

// ================= CSR build =================
__global__ void k_hist(const int* __restrict__ ei, int* __restrict__ deg) {
    int e = blockIdx.x * 256 + threadIdx.x;
    atomicAdd(&deg[ei[EE + e]], 1);
}
__global__ void k_scan1(const int* __restrict__ deg, int* __restrict__ rowptr,
                        int* __restrict__ sums) {
    __shared__ int s[256];
    int base = blockIdx.x * 1024 + threadIdx.x * 4;
    int4 d = *(const int4*)(deg + base);
    int t = d.x + d.y + d.z + d.w;
    s[threadIdx.x] = t;
    __syncthreads();
    for (int off = 1; off < 256; off <<= 1) {
        int v = (threadIdx.x >= off) ? s[threadIdx.x - off] : 0;
        __syncthreads();
        s[threadIdx.x] += v;
        __syncthreads();
    }
    int excl = s[threadIdx.x] - t;
    int4 o; o.x = excl; o.y = excl + d.x; o.z = o.y + d.y; o.w = o.z + d.z;
    *(int4*)(rowptr + base) = o;
    if (threadIdx.x == 255) sums[blockIdx.x] = s[255];
}
__global__ void k_scan2(int* __restrict__ sums) {
    __shared__ int s[256];
    int t = sums[threadIdx.x];
    s[threadIdx.x] = t;
    __syncthreads();
    for (int off = 1; off < 256; off <<= 1) {
        int v = (threadIdx.x >= off) ? s[threadIdx.x - off] : 0;
        __syncthreads();
        s[threadIdx.x] += v;
        __syncthreads();
    }
    sums[threadIdx.x] = s[threadIdx.x] - t;
}
__global__ void k_scan3(int* __restrict__ rowptr, const int* __restrict__ sums,
                        int* __restrict__ fill) {
    int base = blockIdx.x * 1024 + threadIdx.x * 4;
    int add = sums[blockIdx.x];
    int4 r = *(const int4*)(rowptr + base);
    r.x += add; r.y += add; r.z += add; r.w += add;
    *(int4*)(rowptr + base) = r;
    *(int4*)(fill + base) = r;
    if (blockIdx.x == 0 && threadIdx.x == 0) rowptr[NN] = EE;
}
__global__ void k_scatter(const int* __restrict__ ei, const int* __restrict__ ea,
                          int* __restrict__ fill, unsigned* __restrict__ packed) {
    int e = blockIdx.x * 256 + threadIdx.x;
    int dst = ei[EE + e];
    int pos = atomicAdd(&fill[dst], 1);
    unsigned cb = (unsigned)(ea[e * 3 + 0] + ea[e * 3 + 1] * 8 + ea[e * 3 + 2] * 64);
    packed[pos] = (unsigned)ei[e] | (cb << 18);
}

// ============ fused per-layer setup: ctab + BN tables + weight transposes +
// vn16 + pooled zero, one launch (901376 threads = 3521 blocks) ============
__global__ void k_setup(const float* __restrict__ bemb, float* __restrict__ ctab,
                        const float* __restrict__ b1, const float* __restrict__ g1,
                        const float* __restrict__ be1, const float* __restrict__ m1,
                        const float* __restrict__ v1,
                        const float* __restrict__ g3, const float* __restrict__ be3,
                        const float* __restrict__ m3, const float* __restrict__ v3,
                        float* __restrict__ ZA, float* __restrict__ ZB,
                        float* __restrict__ TA, float* __restrict__ TB,
                        float* __restrict__ S3,
                        const float* __restrict__ W1, ushort* __restrict__ W1t,
                        const float* __restrict__ W2, ushort* __restrict__ W2t,
                        const float* __restrict__ W3, ushort* __restrict__ W3t,
                        const float* __restrict__ vn, ushort* __restrict__ vn16,
                        float* __restrict__ pooled) {
    int t = blockIdx.x * 256 + threadIdx.x;
    if (t < 16384) {                       // ctab
        int cb = t >> 5, c = (t & 31) << 2;
        int a0 = cb & 7, a1 = (cb >> 3) & 7, a2 = cb >> 6;
        float4 b0 = *(const float4*)(bemb + (size_t)(0 * VBc + a0) * HH + c);
        float4 b1v = *(const float4*)(bemb + (size_t)(1 * VBc + a1) * HH + c);
        float4 b2v = *(const float4*)(bemb + (size_t)(2 * VBc + a2) * HH + c);
        *(float4*)(ctab + (size_t)cb * HH + c) =
            make_float4(b0.x + b1v.x + b2v.x, b0.y + b1v.y + b2v.y,
                        b0.z + b1v.z + b2v.z, b0.w + b1v.w + b2v.w);
    } else if (t < 16640) {                // BN tables
        int c = t - 16384;
        float s1 = g1[c] * rsqrtf(v1[c] + 1e-5f);
        ZA[c] = s1;
        ZB[c] = ((b1[c] - m1[c]) * s1 + be1[c]) * 0.0625f;
        float s3 = g3[c] * rsqrtf(v3[c] + 1e-5f);
        TA[c] = 16.f * s3;
        TB[c] = be3[c] - m3[c] * s3;
        S3[c] = s3;
    } else if (t < 278784) {               // vn16 (4 elems/thread)
        int i4 = t - 16640;
        float4 v = *(const float4*)(vn + (size_t)i4 * 4);
        ushort4 o;
        o.x = f2h(v.x * 0.0625f); o.y = f2h(v.y * 0.0625f);
        o.z = f2h(v.z * 0.0625f); o.w = f2h(v.w * 0.0625f);
        *(ushort4*)(vn16 + (size_t)i4 * 4) = o;
    } else if (t < 311552) {               // W1t [256][128] <- W1 [128][256]
        int o = t - 278784;
        int c = o >> 7, k = o & 127;
        W1t[o] = f2h(W1[(size_t)k * 256 + c]);
    } else if (t < 344320) {               // W2t [128][256] <- W2 [256][128]
        int o = t - 311552;
        int c = o >> 8, k = o & 255;
        W2t[o] = f2h(W2[(size_t)k * 128 + c]);
    } else if (t < 377088) {               // W3t [256][128] <- W3 [128][256]
        int o = t - 344320;
        int c = o >> 7, k = o & 127;
        W3t[o] = f2h(W3[(size_t)k * 256 + c]);
    } else {                               // pooled zero (4 f32/thread)
        int i4 = t - 377088;
        *(float4*)(pooled + (size_t)i4 * 4) = make_float4(0.f, 0.f, 0.f, 0.f);
    }
}

// CSR aggregation: agg[n] = (1/16) sum relu(16*(h16[src]+vn16[batch[src]])+ctab)
__global__ void k_agg(const ushort* __restrict__ h16, const ushort* __restrict__ vn16,
                      const int* __restrict__ batch,
                      const int* __restrict__ rowptr, const unsigned* __restrict__ packed,
                      const float* __restrict__ ctab, ushort* __restrict__ agg) {
    int n = blockIdx.x * 4 + (threadIdx.x >> 6);
    int lane = threadIdx.x & 63;
    int co = lane * 2;
    int beg = rowptr[n], end = rowptr[n + 1];
    float a0 = 0.f, a1 = 0.f;
    int i = beg;
    for (; i + 1 < end; i += 2) {
        unsigned p0 = packed[i], p1 = packed[i + 1];
        int s0 = p0 & 0x3FFFF, s1 = p1 & 0x3FFFF;
        int c0 = p0 >> 18, c1 = p1 >> 18;
        ushort2 u0 = *(const ushort2*)(h16 + (size_t)s0 * HH + co);
        ushort2 u1 = *(const ushort2*)(h16 + (size_t)s1 * HH + co);
        ushort2 w0 = *(const ushort2*)(vn16 + (size_t)batch[s0] * HH + co);
        ushort2 w1 = *(const ushort2*)(vn16 + (size_t)batch[s1] * HH + co);
        float2 t0 = *(const float2*)(ctab + (size_t)c0 * HH + co);
        float2 t1 = *(const float2*)(ctab + (size_t)c1 * HH + co);
        a0 += fmaxf(16.f * (h2f(u0.x) + h2f(w0.x)) + t0.x, 0.f)
            + fmaxf(16.f * (h2f(u1.x) + h2f(w1.x)) + t1.x, 0.f);
        a1 += fmaxf(16.f * (h2f(u0.y) + h2f(w0.y)) + t0.y, 0.f)
            + fmaxf(16.f * (h2f(u1.y) + h2f(w1.y)) + t1.y, 0.f);
    }
    if (i < end) {
        unsigned p = packed[i];
        int src = p & 0x3FFFF, cb = p >> 18;
        ushort2 u = *(const ushort2*)(h16 + (size_t)src * HH + co);
        ushort2 wv = *(const ushort2*)(vn16 + (size_t)batch[src] * HH + co);
        float2 ct = *(const float2*)(ctab + (size_t)cb * HH + co);
        a0 += fmaxf(16.f * (h2f(u.x) + h2f(wv.x)) + ct.x, 0.f);
        a1 += fmaxf(16.f * (h2f(u.y) + h2f(wv.y)) + ct.y, 0.f);
    }
    ushort2 o; o.x = f2h(a0 * 0.0625f); o.y = f2h(a1 * 0.0625f);
    *(ushort2*)(agg + (size_t)n * HH + co) = o;
}

// ============== mega-kernel v5: 48 KB LDS -> 3 blocks/CU; A in registers;
// h' reuses zs cols 0-127; coalesced h16 store ==============
__global__ void __launch_bounds__(256, 3)
k_conv(ushort* __restrict__ h16, const ushort* __restrict__ agg,
       const ushort* __restrict__ W1t, const ushort* __restrict__ W2t,
       const ushort* __restrict__ W3t,
       const int* __restrict__ batch, const ushort* __restrict__ vn16,
       const float* __restrict__ vnW,
       const float* __restrict__ eps_ptr,
       const float* __restrict__ ZA, const float* __restrict__ ZB,
       const float* __restrict__ b2,
       const float* __restrict__ TA, const float* __restrict__ TB,
       float* __restrict__ pooled) {
    __shared__ ushort zs[64][256];   // z/16; then h'/16 (cols 0-127) + t (cols 128-255)  32 KB
    __shared__ ushort Wb[64][128];   // weight tile 16 KB; [32][256] view for W2
    ushort(*Wb2)[256] = (ushort(*)[256]) & Wb[0][0];
    const int tid = threadIdx.x;
    const int r0 = blockIdx.x * 64;
    const int w = tid >> 6, l = tid & 63, lr = l & 15, lg = l >> 4, lr7 = lr & 7;
    const float eps1 = 1.f + eps_ptr[0];
    const int myrow = w * 16 + lr;
    const int growA = r0 + myrow;
    const int ggA = batch[growA];
    int rl[4], ggs[4];
#pragma unroll
    for (int reg = 0; reg < 4; ++reg) {
        rl[reg] = w * 16 + lg * 4 + reg;
        ggs[reg] = batch[r0 + rl[reg]];
    }

    // ---- A fragments in registers: A/16 = eps1*(h16+vn16) + agg16 ----
    f16x8 af[4];
#pragma unroll
    for (int k0 = 0; k0 < 4; ++k0) {
        int ko = k0 * 32 + lg * 8;
        f16x8 hv = *(const f16x8*)(h16 + (size_t)growA * HH + ko);
        f16x8 vv = *(const f16x8*)(vn16 + (size_t)ggA * HH + ko);
        f16x8 ag = *(const f16x8*)(agg + (size_t)growA * HH + ko);
#pragma unroll
        for (int j = 0; j < 8; ++j)
            af[k0][j] = (f16)(eps1 * ((float)hv[j] + (float)vv[j]) + (float)ag[j]);
    }

    // ---- phase A: z = relu(acc*ZA+ZB)/16 -> zs; W1 in 4 [64][128] quarters ----
    for (int qt = 0; qt < 4; ++qt) {
        __syncthreads();
        {
            int c = tid >> 2, q = tid & 3, c7 = c & 7;
            const ushort* s = W1t + (size_t)(qt * 64 + c) * 128 + q * 32;
#pragma unroll
            for (int j4 = 0; j4 < 4; ++j4)
                *(f16x8*)&Wb[c][((q * 4 + j4) ^ c7) << 3] = *(const f16x8*)(s + j4 * 8);
        }
        __syncthreads();
        f32x4 acc[4] = {};
#pragma unroll
        for (int k0 = 0; k0 < 4; ++k0) {
            int sb = ((k0 * 4 + lg) ^ lr7) << 3;
#pragma unroll
            for (int fc = 0; fc < 4; ++fc) {
                f16x8 bf = *(const f16x8*)&Wb[fc * 16 + lr][sb];
                acc[fc] = __builtin_amdgcn_mfma_f32_16x16x32_f16(af[k0], bf, acc[fc], 0, 0, 0);
            }
        }
#pragma unroll
        for (int fc = 0; fc < 4; ++fc) {
            int col = qt * 64 + fc * 16 + lr;
            float za = ZA[col], zb = ZB[col];
#pragma unroll
            for (int reg = 0; reg < 4; ++reg) {
                float zv = fmaxf(acc[fc][reg] * za + zb, 0.f);
                zs[rl[reg]][swz(col, rl[reg])] = f2h(zv);
            }
        }
    }

    // ---- phase B: h' = acc*16+b2; W2 in 4 [32][256] stages, acc2 persists ----
    f32x4 acc2[8] = {};
    for (int st = 0; st < 4; ++st) {
        __syncthreads();
        {
            int c = tid >> 3, q = tid & 7, c7 = c & 7;
            const ushort* s = W2t + (size_t)(st * 32 + c) * 256 + q * 32;
#pragma unroll
            for (int j4 = 0; j4 < 4; ++j4)
                *(f16x8*)&Wb2[c][((q * 4 + j4) ^ c7) << 3] = *(const f16x8*)(s + j4 * 8);
        }
        __syncthreads();
#pragma unroll
        for (int k0 = 0; k0 < 8; ++k0) {
            int sb = ((k0 * 4 + lg) ^ lr7) << 3;
            f16x8 az = *(const f16x8*)&zs[myrow][sb];
#pragma unroll
            for (int fc = 0; fc < 2; ++fc) {
                f16x8 bf = *(const f16x8*)&Wb2[fc * 16 + lr][sb];
                acc2[st * 2 + fc] =
                    __builtin_amdgcn_mfma_f32_16x16x32_f16(az, bf, acc2[st * 2 + fc], 0, 0, 0);
            }
        }
    }
    __syncthreads();   // all waves done reading z before cols 0-127 are overwritten
    // h'/16 -> zs cols 0-127 (wave-private rows)
#pragma unroll
    for (int st = 0; st < 4; ++st) {
#pragma unroll
        for (int fc = 0; fc < 2; ++fc) {
            int col = st * 32 + fc * 16 + lr;
            float bb = b2[col];
#pragma unroll
            for (int reg = 0; reg < 4; ++reg) {
                float hv = acc2[st * 2 + fc][reg] * 16.f + bb;
                zs[rl[reg]][swz(col, rl[reg])] = f2h(hv * 0.0625f);
            }
        }
    }
    // coalesced h16 store (wave-private rows; in-wave LDS dependency)
    {
        int row = tid >> 2, q = tid & 3, r7 = row & 7;
#pragma unroll
        for (int j4 = 0; j4 < 4; ++j4) {
            f16x8 v = *(const f16x8*)&zs[row][((q * 4 + j4) ^ r7) << 3];
            *(f16x8*)(h16 + (size_t)(r0 + row) * HH + q * 32 + j4 * 8) = v;
        }
    }

    // ---- phase C: t = relu(acc*TA + vnW' + TB); W3 quarters; pool per 128-col half ----
    for (int pr = 0; pr < 2; ++pr) {
#pragma unroll
        for (int sub = 0; sub < 2; ++sub) {
            int qt = pr * 2 + sub;
            __syncthreads();
            {
                int c = tid >> 2, q = tid & 3, c7 = c & 7;
                const ushort* s = W3t + (size_t)(qt * 64 + c) * 128 + q * 32;
#pragma unroll
                for (int j4 = 0; j4 < 4; ++j4)
                    *(f16x8*)&Wb[c][((q * 4 + j4) ^ c7) << 3] = *(const f16x8*)(s + j4 * 8);
            }
            __syncthreads();
            f32x4 acc3[4] = {};
#pragma unroll
            for (int k0 = 0; k0 < 4; ++k0) {
                int sb = ((k0 * 4 + lg) ^ lr7) << 3;
                f16x8 ah = *(const f16x8*)&zs[myrow][sb];
#pragma unroll
                for (int fc = 0; fc < 4; ++fc) {
                    f16x8 bf = *(const f16x8*)&Wb[fc * 16 + lr][sb];
                    acc3[fc] = __builtin_amdgcn_mfma_f32_16x16x32_f16(ah, bf, acc3[fc], 0, 0, 0);
                }
            }
#pragma unroll
            for (int fc = 0; fc < 4; ++fc) {
                int colg = qt * 64 + fc * 16 + lr;
                int colL = 128 + sub * 64 + fc * 16 + lr;
                float ta = TA[colg], tb = TB[colg];
#pragma unroll
                for (int reg = 0; reg < 4; ++reg) {
                    float tv = fmaxf(acc3[fc][reg] * ta + vnW[(size_t)ggs[reg] * 256 + colg] + tb, 0.f);
                    zs[rl[reg]][swz(colL, rl[reg])] = f2h(tv);
                }
            }
        }
        __syncthreads();
        {   // pool 128 cols (pr*128+c): 2 threads/col, 32 rows each
            int c = tid & 127, half = tid >> 7;
            int gcol = pr * 128 + c;
            int colL = 128 + c;
            float s = 0.f;
            int cur = batch[r0 + half * 32];
            for (int r = half * 32; r < half * 32 + 32; ++r) {
                int gg = batch[r0 + r];
                if (gg != cur) {
                    atomicAdd(&pooled[(size_t)cur * 256 + gcol], s);
                    s = 0.f; cur = gg;
                }
                s += h2f(zs[r][swz(colL, r)]);
            }
            atomicAdd(&pooled[(size_t)cur * 256 + gcol], s);
        }
        __syncthreads();
    }
}

// ---------------- small f32 GEMM (GEMM3a, GEMM4) ----------------
enum { E_BIAS = 0, E_BNRELU = 1 };
template <int EMODE>
__global__ void __launch_bounds__(256)
gemm_k(const void* __restrict__ Av, const float* __restrict__ B,
       const float* __restrict__ bias,
       const float* __restrict__ g_, const float* __restrict__ b_,
       const float* __restrict__ m_, const float* __restrict__ v_,
       const float* __restrict__ scp,
       void* __restrict__ outv, int K, int Nc) {
    __shared__ float As[64][33];
    __shared__ float Bs[32][64];
    const int tid = threadIdx.x;
    const int row0 = blockIdx.x * 64;
    const int col0 = blockIdx.y * 64;
    float acc[4][4] = {};
    const int tx = tid & 15, ty = tid >> 4;
    for (int k0 = 0; k0 < K; k0 += 32) {
#pragma unroll
        for (int p = 0; p < 2; ++p) {
            int idx = p * 256 + tid;
            {
                int r = idx >> 3, c = (idx & 7) << 2;
                size_t aoff = (size_t)(row0 + r) * K + k0 + c;
                float4 va = *(const float4*)((const float*)Av + aoff);
                As[r][c + 0] = va.x; As[r][c + 1] = va.y;
                As[r][c + 2] = va.z; As[r][c + 3] = va.w;
            }
            {
                int kr = idx >> 4, cc = (idx & 15) << 2;
                *(float4*)&Bs[kr][cc] =
                    *(const float4*)(B + (size_t)(k0 + kr) * Nc + col0 + cc);
            }
        }
        __syncthreads();
#pragma unroll
        for (int k = 0; k < 32; ++k) {
            float4 bv = *(const float4*)&Bs[k][tx << 2];
            float a0 = As[ty * 4 + 0][k];
            float a1 = As[ty * 4 + 1][k];
            float a2 = As[ty * 4 + 2][k];
            float a3 = As[ty * 4 + 3][k];
            acc[0][0] += a0 * bv.x; acc[0][1] += a0 * bv.y; acc[0][2] += a0 * bv.z; acc[0][3] += a0 * bv.w;
            acc[1][0] += a1 * bv.x; acc[1][1] += a1 * bv.y; acc[1][2] += a1 * bv.z; acc[1][3] += a1 * bv.w;
            acc[2][0] += a2 * bv.x; acc[2][1] += a2 * bv.y; acc[2][2] += a2 * bv.z; acc[2][3] += a2 * bv.w;
            acc[3][0] += a3 * bv.x; acc[3][1] += a3 * bv.y; acc[3][2] += a3 * bv.z; acc[3][3] += a3 * bv.w;
        }
        __syncthreads();
    }
#pragma unroll
    for (int j = 0; j < 4; ++j) {
        int gr = row0 + ty * 4 + j;
        float vals[4];
#pragma unroll
        for (int lx = 0; lx < 4; ++lx) {
            int gc = col0 + (tx << 2) + lx;
            float val = acc[j][lx];
            if (EMODE == E_BIAS) {
                float v = val + bias[gc];
                if (scp) v *= scp[gc];
                vals[lx] = v;
            } else {
                float y = val + bias[gc];
                float s = g_[gc] * rsqrtf(v_[gc] + 1e-5f);
                y = (y - m_[gc]) * s + b_[gc];
                vals[lx] = fmaxf(y, 0.f);
            }
        }
        *(float4*)((float*)outv + (size_t)gr * Nc + col0 + (tx << 2)) =
            make_float4(vals[0], vals[1], vals[2], vals[3]);
    }
}

// ---------------- final head ----------------
__global__ void k_final(const float* __restrict__ vn, const float* __restrict__ pW1,
                        const float* __restrict__ pb1, const float* __restrict__ pW2,
                        const float* __restrict__ pb2, float* __restrict__ out) {
    int g = blockIdx.x;
    int j = threadIdx.x;
    __shared__ float vrow[HH];
    __shared__ float red[HH];
    vrow[j] = vn[(size_t)g * HH + j];
    __syncthreads();
    float acc = pb1[j];
    for (int k = 0; k < HH; ++k) acc = fmaf(vrow[k], pW1[k * HH + j], acc);
    red[j] = fmaxf(acc, 0.f) * pW2[j];
    __syncthreads();
    for (int s = 64; s > 0; s >>= 1) {
        if (j < s) red[j] += red[j + s];
        __syncthreads();
    }
    if (j == 0) out[g] = fminf(fmaxf(red[0] + pb2[0], 0.f), 50.f);
}

extern "C" void kernel_launch(void* const* d_in, const int* in_sizes, int n_in,
                              void* d_out, int out_size, void* d_ws, size_t ws_size,
                              hipStream_t stream) {
    const int*   x        = (const int*)  d_in[0];
    const int*   ei       = (const int*)  d_in[1];
    const int*   ea       = (const int*)  d_in[2];
    const int*   batch    = (const int*)  d_in[3];
    const float* atom_emb = (const float*)d_in[4];
    const float* vn_emb   = (const float*)d_in[5];
    const float* bond_emb = (const float*)d_in[6];
    const float* conv_eps = (const float*)d_in[7];
    const float* conv_W1  = (const float*)d_in[8];
    const float* conv_b1  = (const float*)d_in[9];
    const float* cbn_g    = (const float*)d_in[10];
    const float* cbn_b    = (const float*)d_in[11];
    const float* cbn_m    = (const float*)d_in[12];
    const float* cbn_v    = (const float*)d_in[13];
    const float* conv_W2  = (const float*)d_in[14];
    const float* conv_b2  = (const float*)d_in[15];
    const float* vn1_W    = (const float*)d_in[16];
    const float* vn1_b    = (const float*)d_in[17];
    const float* vn1_g    = (const float*)d_in[18];
    const float* vn1_be   = (const float*)d_in[19];
    const float* vn1_m    = (const float*)d_in[20];
    const float* vn1_v    = (const float*)d_in[21];
    const float* vn2_W    = (const float*)d_in[22];
    const float* vn2_b    = (const float*)d_in[23];
    const float* vn2_g    = (const float*)d_in[24];
    const float* vn2_be   = (const float*)d_in[25];
    const float* vn2_m    = (const float*)d_in[26];
    const float* vn2_v    = (const float*)d_in[27];
    const float* pW1      = (const float*)d_in[28];
    const float* pb1      = (const float*)d_in[29];
    const float* pW2      = (const float*)d_in[30];
    const float* pb2      = (const float*)d_in[31];

    // ---- workspace layout (~165 MB) ----
    char* base = (char*)d_ws;
    ushort*   h16    = (ushort*)base;                                 // NN*HH fp16 (state/16)
    ushort*   agg    = h16 + (size_t)NN * HH;                         // NN*HH fp16
    unsigned* packed = (unsigned*)(agg + (size_t)NN * HH);            // EE u32
    int*      rowptr = (int*)(packed + EE);                           // NN+4
    int*      fill   = rowptr + NN + 4;                               // NN
    float*    ctab   = (float*)(fill + NN);                           // 512*HH f32
    int*      sums   = (int*)(ctab + 512 * HH);                       // 256
    ushort*   W1t    = (ushort*)(sums + 256);                         // 256*128
    ushort*   W2t    = W1t + 256 * 128;                               // 128*256
    ushort*   W3t    = W2t + 128 * 256;                               // 256*128
    float*    ZA     = (float*)(W3t + 256 * 128);                     // 256
    float*    ZB     = ZA + 256;
    float*    TA     = ZB + 256;
    float*    TB     = TA + 256;
    float*    S3     = TB + 256;
    float*    vn     = S3 + 256;                                      // GG*HH f32
    ushort*   vn16   = (ushort*)(vn + (size_t)GG * HH);               // GG*HH fp16
    float*    vnW    = (float*)(vn16 + (size_t)GG * HH);              // GG*256
    float*    pooled = vnW + (size_t)GG * 256;                        // GG*256
    float*    out    = (float*)d_out;

    // ---- setup ----
    k_zero<<<256, 256, 0, stream>>>((float*)fill);
    k_hist<<<EE / 256, 256, 0, stream>>>(ei, fill);
    k_scan1<<<256, 256, 0, stream>>>(fill, rowptr, sums);
    k_scan2<<<1, 256, 0, stream>>>(sums);
    k_scan3<<<256, 256, 0, stream>>>(rowptr, sums, fill);
    k_scatter<<<EE / 256, 256, 0, stream>>>(ei, ea, fill, packed);
    k_atom<<<NN * 32 / 256, 256, 0, stream>>>(x, atom_emb, h16);
    k_init_vn<<<GG * HH / 4 / 256, 256, 0, stream>>>(vn_emb, vn);

    for (int i = 0; i < 4; ++i) {
        k_setup<<<3521, 256, 0, stream>>>(
            bond_emb + (size_t)i * FBc * VBc * HH, ctab,
            conv_b1 + i * 256, cbn_g + i * 256, cbn_b + i * 256,
            cbn_m + i * 256, cbn_v + i * 256,
            vn1_g + i * 256, vn1_be + i * 256, vn1_m + i * 256, vn1_v + i * 256,
            ZA, ZB, TA, TB, S3,
            conv_W1 + (size_t)i * HH * 256, W1t,
            conv_W2 + (size_t)i * 256 * HH, W2t,
            vn1_W + (size_t)i * 256 * 256 + 128 * 256, W3t,
            vn, vn16, pooled);

        k_agg<<<NN / 4, 256, 0, stream>>>(h16, vn16, batch, rowptr, packed, ctab, agg);

        // GEMM3a: vnW' = (vn @ vn1_W[:128] + vn1_b) * s3
        {
            dim3 g3(GG / 64, 4);
            gemm_k<E_BIAS><<<g3, 256, 0, stream>>>(
                vn, vn1_W + (size_t)i * 256 * 256, vn1_b + i * 256,
                nullptr, nullptr, nullptr, nullptr, S3, vnW, HH, 256);
        }

        // mega-kernel v5
        k_conv<<<NN / 64, 256, 0, stream>>>(
            h16, agg, W1t, W2t, W3t, batch, vn16, vnW, conv_eps + i,
            ZA, ZB, conv_b2 + i * HH, TA, TB, pooled);

        // GEMM4: vn = relu(bn(pooled @ vn2_W + vn2_b))
        {
            dim3 g4(GG / 64, 2);
            gemm_k<E_BNRELU><<<g4, 256, 0, stream>>>(
                pooled, vn2_W + (size_t)i * 256 * HH, vn2_b + i * HH,
                vn2_g + i * HH, vn2_be + i * HH, vn2_m + i * HH, vn2_v + i * HH,
                nullptr, vn, 256, HH);
        }
    }
    k_final<<<GG, 128, 0, stream>>>(vn, pW1, pb1, pW2, pb2, out);
}

// Round 15
// 1543.328 us; speedup vs baseline: 1.7769x; 1.0023x over previous
//
#include <hip/hip_runtime.h>
#include <hip/hip_fp16.h>

#define NN 262144
#define EE 1048576
#define GG 8192
#define HH 128
#define FBc 3
#define VAc 64
#define VBc 8
#define FAc 9

typedef _Float16 f16;
typedef _Float16 f16x8 __attribute__((ext_vector_type(8)));
typedef float f32x4 __attribute__((ext_vector_type(4)));

__device__ __forceinline__ float h2f(ushort u) {
    __half h; *(ushort*)&h = u; return __half2float(h);
}
__device__ __forceinline__ ushort f2h(float f) {
    __half h = __float2half_rn(f); return *(ushort*)&h;
}
// LDS swizzle: 16B-block XOR within a row
__device__ __forceinline__ int swz(int col, int row) {
    return (((col >> 3) ^ (row & 7)) << 3) | (col & 7);
}

// ---------------- zero fill ----------------
__global__ void k_zero(float* __restrict__ p) {
    size_t i = (size_t)(blockIdx.x * 256 + threadIdx.x) * 4;
    *(float4*)(p + i) = make_float4(0.f, 0.f, 0.f, 0.f);
}

// ---------------- atom encoder: h16 = (sum emb)/16 fp16 ----------------
__global__ void k_atom(const int* __restrict__ x, const float* __restrict__ emb,
                       ushort* __restrict__ h16) {
    int t = blockIdx.x * 256 + threadIdx.x;
    int n = t >> 5, c = (t & 31) << 2;
    if (n >= NN) return;
    float4 a = make_float4(0.f, 0.f, 0.f, 0.f);
#pragma unroll
    for (int f = 0; f < FAc; ++f) {
        int v = x[n * FAc + f];
        float4 e = *(const float4*)(emb + ((size_t)(f * VAc + v)) * HH + c);
        a.x += e.x; a.y += e.y; a.z += e.z; a.w += e.w;
    }
    ushort4 o;
    o.x = f2h(a.x * 0.0625f); o.y = f2h(a.y * 0.0625f);
    o.z = f2h(a.z * 0.0625f); o.w = f2h(a.w * 0.0625f);
    *(ushort4*)(h16 + (size_t)n * HH + c) = o;
}

// ---------------- vn init ----------------
__global__ void k_init_vn(const float* __restrict__ vn_emb, float* __restrict__ vn) {
    int t = blockIdx.x * 256 + threadIdx.x;
    int g = t >> 5, c = (t & 31) << 2;
    *(float4*)(vn + (size_t)g * HH + c) = *(const float4*)(vn_emb + c);
}

// ================= CSR build =================
__global__ void k_hist(const int* __restrict__ ei, int* __restrict__ deg) {
    int e = blockIdx.x * 256 + threadIdx.x;
    atomicAdd(&deg[ei[EE + e]], 1);
}
__global__ void k_scan1(const int* __restrict__ deg, int* __restrict__ rowptr,
                        int* __restrict__ sums) {
    __shared__ int s[256];
    int base = blockIdx.x * 1024 + threadIdx.x * 4;
    int4 d = *(const int4*)(deg + base);
    int t = d.x + d.y + d.z + d.w;
    s[threadIdx.x] = t;
    __syncthreads();
    for (int off = 1; off < 256; off <<= 1) {
        int v = (threadIdx.x >= off) ? s[threadIdx.x - off] : 0;
        __syncthreads();
        s[threadIdx.x] += v;
        __syncthreads();
    }
    int excl = s[threadIdx.x] - t;
    int4 o; o.x = excl; o.y = excl + d.x; o.z = o.y + d.y; o.w = o.z + d.z;
    *(int4*)(rowptr + base) = o;
    if (threadIdx.x == 255) sums[blockIdx.x] = s[255];
}
__global__ void k_scan2(int* __restrict__ sums) {
    __shared__ int s[256];
    int t = sums[threadIdx.x];
    s[threadIdx.x] = t;
    __syncthreads();
    for (int off = 1; off < 256; off <<= 1) {
        int v = (threadIdx.x >= off) ? s[threadIdx.x - off] : 0;
        __syncthreads();
        s[threadIdx.x] += v;
        __syncthreads();
    }
    sums[threadIdx.x] = s[threadIdx.x] - t;
}
__global__ void k_scan3(int* __restrict__ rowptr, const int* __restrict__ sums,
                        int* __restrict__ fill) {
    int base = blockIdx.x * 1024 + threadIdx.x * 4;
    int add = sums[blockIdx.x];
    int4 r = *(const int4*)(rowptr + base);
    r.x += add; r.y += add; r.z += add; r.w += add;
    *(int4*)(rowptr + base) = r;
    *(int4*)(fill + base) = r;
    if (blockIdx.x == 0 && threadIdx.x == 0) rowptr[NN] = EE;
}
__global__ void k_scatter(const int* __restrict__ ei, const int* __restrict__ ea,
                          int* __restrict__ fill, unsigned* __restrict__ packed) {
    int e = blockIdx.x * 256 + threadIdx.x;
    int dst = ei[EE + e];
    int pos = atomicAdd(&fill[dst], 1);
    unsigned cb = (unsigned)(ea[e * 3 + 0] + ea[e * 3 + 1] * 8 + ea[e * 3 + 2] * 64);
    packed[pos] = (unsigned)ei[e] | (cb << 18);
}

// ============ fused per-layer setup: ct16 + BN tables + weight transposes +
// vn16 + pooled zero, one launch ============
__global__ void k_setup(const float* __restrict__ bemb, ushort* __restrict__ ct16,
                        const float* __restrict__ b1, const float* __restrict__ g1,
                        const float* __restrict__ be1, const float* __restrict__ m1,
                        const float* __restrict__ v1,
                        const float* __restrict__ g3, const float* __restrict__ be3,
                        const float* __restrict__ m3, const float* __restrict__ v3,
                        float* __restrict__ ZA, float* __restrict__ ZB,
                        float* __restrict__ TA, float* __restrict__ TB,
                        float* __restrict__ S3,
                        const float* __restrict__ W1, ushort* __restrict__ W1t,
                        const float* __restrict__ W2, ushort* __restrict__ W2t,
                        const float* __restrict__ W3, ushort* __restrict__ W3t,
                        const float* __restrict__ vn, ushort* __restrict__ vn16,
                        float* __restrict__ pooled) {
    int t = blockIdx.x * 256 + threadIdx.x;
    if (t < 16384) {                       // ct16 = (sum bemb)/16 fp16
        int cb = t >> 5, c = (t & 31) << 2;
        int a0 = cb & 7, a1 = (cb >> 3) & 7, a2 = cb >> 6;
        float4 b0 = *(const float4*)(bemb + (size_t)(0 * VBc + a0) * HH + c);
        float4 b1v = *(const float4*)(bemb + (size_t)(1 * VBc + a1) * HH + c);
        float4 b2v = *(const float4*)(bemb + (size_t)(2 * VBc + a2) * HH + c);
        ushort4 o;
        o.x = f2h((b0.x + b1v.x + b2v.x) * 0.0625f);
        o.y = f2h((b0.y + b1v.y + b2v.y) * 0.0625f);
        o.z = f2h((b0.z + b1v.z + b2v.z) * 0.0625f);
        o.w = f2h((b0.w + b1v.w + b2v.w) * 0.0625f);
        *(ushort4*)(ct16 + (size_t)cb * HH + c) = o;
    } else if (t < 16640) {                // BN tables
        int c = t - 16384;
        float s1 = g1[c] * rsqrtf(v1[c] + 1e-5f);
        ZA[c] = s1;
        ZB[c] = ((b1[c] - m1[c]) * s1 + be1[c]) * 0.0625f;
        float s3 = g3[c] * rsqrtf(v3[c] + 1e-5f);
        TA[c] = 16.f * s3;
        TB[c] = be3[c] - m3[c] * s3;
        S3[c] = s3;
    } else if (t < 278784) {               // vn16 (4 elems/thread)
        int i4 = t - 16640;
        float4 v = *(const float4*)(vn + (size_t)i4 * 4);
        ushort4 o;
        o.x = f2h(v.x * 0.0625f); o.y = f2h(v.y * 0.0625f);
        o.z = f2h(v.z * 0.0625f); o.w = f2h(v.w * 0.0625f);
        *(ushort4*)(vn16 + (size_t)i4 * 4) = o;
    } else if (t < 311552) {               // W1t [256][128] <- W1 [128][256]
        int o = t - 278784;
        int c = o >> 7, k = o & 127;
        W1t[o] = f2h(W1[(size_t)k * 256 + c]);
    } else if (t < 344320) {               // W2t [128][256] <- W2 [256][128]
        int o = t - 311552;
        int c = o >> 8, k = o & 255;
        W2t[o] = f2h(W2[(size_t)k * 128 + c]);
    } else if (t < 377088) {               // W3t [256][128] <- W3 [128][256]
        int o = t - 344320;
        int c = o >> 7, k = o & 127;
        W3t[o] = f2h(W3[(size_t)k * 256 + c]);
    } else {                               // pooled zero (4 f32/thread)
        int i4 = t - 377088;
        *(float4*)(pooled + (size_t)i4 * 4) = make_float4(0.f, 0.f, 0.f, 0.f);
    }
}

// ============== mega-kernel v6: fused edge-gather + conv MLP + vn1-bottom + pool.
// Reads h16in (prev state, never written here); writes h16out. 48 KB LDS, 3 blk/CU.
__global__ void __launch_bounds__(256, 3)
k_conv(const ushort* __restrict__ h16in, ushort* __restrict__ h16out,
       const int* __restrict__ rowptr, const unsigned* __restrict__ packed,
       const ushort* __restrict__ ct16,
       const ushort* __restrict__ W1t, const ushort* __restrict__ W2t,
       const ushort* __restrict__ W3t,
       const int* __restrict__ batch, const ushort* __restrict__ vn16,
       const float* __restrict__ vnW,
       const float* __restrict__ eps_ptr,
       const float* __restrict__ ZA, const float* __restrict__ ZB,
       const float* __restrict__ b2,
       const float* __restrict__ TA, const float* __restrict__ TB,
       float* __restrict__ pooled) {
    __shared__ ushort zs[64][256];   // agg staging (cols 0-127) -> z -> h'/16 + t   32 KB
    __shared__ ushort Wb[64][128];   // weight tile 16 KB; [32][256] view for W2
    ushort(*Wb2)[256] = (ushort(*)[256]) & Wb[0][0];
    const int tid = threadIdx.x;
    const int r0 = blockIdx.x * 64;
    const int w = tid >> 6, l = tid & 63, lr = l & 15, lg = l >> 4, lr7 = lr & 7;
    const float eps1 = 1.f + eps_ptr[0];
    const int myrow = w * 16 + lr;
    const int growA = r0 + myrow;
    const int ggA = batch[growA];
    int rl[4], ggs[4];
#pragma unroll
    for (int reg = 0; reg < 4; ++reg) {
        rl[reg] = w * 16 + lg * 4 + reg;
        ggs[reg] = batch[r0 + rl[reg]];
    }

    // ---- fused edge gather: agg/16 -> zs cols 0-127 ----
    // 16 groups of 16 lanes; group g handles rows g*4..g*4+3; lane = 8 channels.
    {
        int grp = tid >> 4, ln = tid & 15;
        int ch0 = ln * 8;
        for (int rr = 0; rr < 4; ++rr) {
            int row = grp * 4 + rr;
            int beg = rowptr[r0 + row], end = rowptr[r0 + row + 1];
            float ac[8] = {0.f, 0.f, 0.f, 0.f, 0.f, 0.f, 0.f, 0.f};
            int e = beg;
            for (; e + 1 < end; e += 2) {
                unsigned p0 = packed[e], p1 = packed[e + 1];
                int s0 = p0 & 0x3FFFF, s1 = p1 & 0x3FFFF;
                int c0 = p0 >> 18, c1 = p1 >> 18;
                f16x8 h0 = *(const f16x8*)(h16in + (size_t)s0 * HH + ch0);
                f16x8 h1 = *(const f16x8*)(h16in + (size_t)s1 * HH + ch0);
                f16x8 v0 = *(const f16x8*)(vn16 + (size_t)batch[s0] * HH + ch0);
                f16x8 v1 = *(const f16x8*)(vn16 + (size_t)batch[s1] * HH + ch0);
                f16x8 t0 = *(const f16x8*)(ct16 + (size_t)c0 * HH + ch0);
                f16x8 t1 = *(const f16x8*)(ct16 + (size_t)c1 * HH + ch0);
#pragma unroll
                for (int j = 0; j < 8; ++j) {
                    ac[j] += fmaxf((float)h0[j] + (float)v0[j] + (float)t0[j], 0.f)
                           + fmaxf((float)h1[j] + (float)v1[j] + (float)t1[j], 0.f);
                }
            }
            if (e < end) {
                unsigned p = packed[e];
                int src = p & 0x3FFFF, cb = p >> 18;
                f16x8 hv = *(const f16x8*)(h16in + (size_t)src * HH + ch0);
                f16x8 vv = *(const f16x8*)(vn16 + (size_t)batch[src] * HH + ch0);
                f16x8 ct = *(const f16x8*)(ct16 + (size_t)cb * HH + ch0);
#pragma unroll
                for (int j = 0; j < 8; ++j)
                    ac[j] += fmaxf((float)hv[j] + (float)vv[j] + (float)ct[j], 0.f);
            }
            f16x8 o;
#pragma unroll
            for (int j = 0; j < 8; ++j) o[j] = (f16)ac[j];
            *(f16x8*)&zs[row][((ch0 >> 3) ^ (row & 7)) << 3] = o;
        }
    }
    __syncthreads();

    // ---- A fragments: A/16 = eps1*(h16+vn16) + agg16(zs) ----
    f16x8 af[4];
#pragma unroll
    for (int k0 = 0; k0 < 4; ++k0) {
        int ko = k0 * 32 + lg * 8;
        f16x8 hv = *(const f16x8*)(h16in + (size_t)growA * HH + ko);
        f16x8 vv = *(const f16x8*)(vn16 + (size_t)ggA * HH + ko);
        f16x8 ag = *(const f16x8*)&zs[myrow][((ko >> 3) ^ (myrow & 7)) << 3];
#pragma unroll
        for (int j = 0; j < 8; ++j)
            af[k0][j] = (f16)(eps1 * ((float)hv[j] + (float)vv[j]) + (float)ag[j]);
    }

    // ---- phase A: z = relu(acc*ZA+ZB)/16 -> zs; W1 in 4 [64][128] quarters ----
    for (int qt = 0; qt < 4; ++qt) {
        __syncthreads();
        {
            int c = tid >> 2, q = tid & 3, c7 = c & 7;
            const ushort* s = W1t + (size_t)(qt * 64 + c) * 128 + q * 32;
#pragma unroll
            for (int j4 = 0; j4 < 4; ++j4)
                *(f16x8*)&Wb[c][((q * 4 + j4) ^ c7) << 3] = *(const f16x8*)(s + j4 * 8);
        }
        __syncthreads();
        f32x4 acc[4] = {};
#pragma unroll
        for (int k0 = 0; k0 < 4; ++k0) {
            int sb = ((k0 * 4 + lg) ^ lr7) << 3;
#pragma unroll
            for (int fc = 0; fc < 4; ++fc) {
                f16x8 bf = *(const f16x8*)&Wb[fc * 16 + lr][sb];
                acc[fc] = __builtin_amdgcn_mfma_f32_16x16x32_f16(af[k0], bf, acc[fc], 0, 0, 0);
            }
        }
#pragma unroll
        for (int fc = 0; fc < 4; ++fc) {
            int col = qt * 64 + fc * 16 + lr;
            float za = ZA[col], zb = ZB[col];
#pragma unroll
            for (int reg = 0; reg < 4; ++reg) {
                float zv = fmaxf(acc[fc][reg] * za + zb, 0.f);
                zs[rl[reg]][swz(col, rl[reg])] = f2h(zv);
            }
        }
    }

    // ---- phase B: h' = acc*16+b2; W2 in 4 [32][256] stages, acc2 persists ----
    f32x4 acc2[8] = {};
    for (int st = 0; st < 4; ++st) {
        __syncthreads();
        {
            int c = tid >> 3, q = tid & 7, c7 = c & 7;
            const ushort* s = W2t + (size_t)(st * 32 + c) * 256 + q * 32;
#pragma unroll
            for (int j4 = 0; j4 < 4; ++j4)
                *(f16x8*)&Wb2[c][((q * 4 + j4) ^ c7) << 3] = *(const f16x8*)(s + j4 * 8);
        }
        __syncthreads();
#pragma unroll
        for (int k0 = 0; k0 < 8; ++k0) {
            int sb = ((k0 * 4 + lg) ^ lr7) << 3;
            f16x8 az = *(const f16x8*)&zs[myrow][sb];
#pragma unroll
            for (int fc = 0; fc < 2; ++fc) {
                f16x8 bf = *(const f16x8*)&Wb2[fc * 16 + lr][sb];
                acc2[st * 2 + fc] =
                    __builtin_amdgcn_mfma_f32_16x16x32_f16(az, bf, acc2[st * 2 + fc], 0, 0, 0);
            }
        }
    }
    __syncthreads();   // all waves done reading z before cols 0-127 are overwritten
    // h'/16 -> zs cols 0-127 (wave-private rows)
#pragma unroll
    for (int st = 0; st < 4; ++st) {
#pragma unroll
        for (int fc = 0; fc < 2; ++fc) {
            int col = st * 32 + fc * 16 + lr;
            float bb = b2[col];
#pragma unroll
            for (int reg = 0; reg < 4; ++reg) {
                float hv = acc2[st * 2 + fc][reg] * 16.f + bb;
                zs[rl[reg]][swz(col, rl[reg])] = f2h(hv * 0.0625f);
            }
        }
    }
    // coalesced h16out store (wave-private rows; in-wave LDS dependency)
    {
        int row = tid >> 2, q = tid & 3, r7 = row & 7;
#pragma unroll
        for (int j4 = 0; j4 < 4; ++j4) {
            f16x8 v = *(const f16x8*)&zs[row][((q * 4 + j4) ^ r7) << 3];
            *(f16x8*)(h16out + (size_t)(r0 + row) * HH + q * 32 + j4 * 8) = v;
        }
    }

    // ---- phase C: t = relu(acc*TA + vnW' + TB); W3 quarters; pool per 128-col half ----
    for (int pr = 0; pr < 2; ++pr) {
#pragma unroll
        for (int sub = 0; sub < 2; ++sub) {
            int qt = pr * 2 + sub;
            __syncthreads();
            {
                int c = tid >> 2, q = tid & 3, c7 = c & 7;
                const ushort* s = W3t + (size_t)(qt * 64 + c) * 128 + q * 32;
#pragma unroll
                for (int j4 = 0; j4 < 4; ++j4)
                    *(f16x8*)&Wb[c][((q * 4 + j4) ^ c7) << 3] = *(const f16x8*)(s + j4 * 8);
            }
            __syncthreads();
            f32x4 acc3[4] = {};
#pragma unroll
            for (int k0 = 0; k0 < 4; ++k0) {
                int sb = ((k0 * 4 + lg) ^ lr7) << 3;
                f16x8 ah = *(const f16x8*)&zs[myrow][sb];
#pragma unroll
                for (int fc = 0; fc < 4; ++fc) {
                    f16x8 bf = *(const f16x8*)&Wb[fc * 16 + lr][sb];
                    acc3[fc] = __builtin_amdgcn_mfma_f32_16x16x32_f16(ah, bf, acc3[fc], 0, 0, 0);
                }
            }
#pragma unroll
            for (int fc = 0; fc < 4; ++fc) {
                int colg = qt * 64 + fc * 16 + lr;
                int colL = 128 + sub * 64 + fc * 16 + lr;
                float ta = TA[colg], tb = TB[colg];
#pragma unroll
                for (int reg = 0; reg < 4; ++reg) {
                    float tv = fmaxf(acc3[fc][reg] * ta + vnW[(size_t)ggs[reg] * 256 + colg] + tb, 0.f);
                    zs[rl[reg]][swz(colL, rl[reg])] = f2h(tv);
                }
            }
        }
        __syncthreads();
        {   // pool 128 cols (pr*128+c): 2 threads/col, 32 rows each
            int c = tid & 127, half = tid >> 7;
            int gcol = pr * 128 + c;
            int colL = 128 + c;
            float s = 0.f;
            int cur = batch[r0 + half * 32];
            for (int r = half * 32; r < half * 32 + 32; ++r) {
                int gg = batch[r0 + r];
                if (gg != cur) {
                    atomicAdd(&pooled[(size_t)cur * 256 + gcol], s);
                    s = 0.f; cur = gg;
                }
                s += h2f(zs[r][swz(colL, r)]);
            }
            atomicAdd(&pooled[(size_t)cur * 256 + gcol], s);
        }
        __syncthreads();
    }
}

// ---------------- small f32 GEMM (GEMM3a, GEMM4) ----------------
enum { E_BIAS = 0, E_BNRELU = 1 };
template <int EMODE>
__global__ void __launch_bounds__(256)
gemm_k(const void* __restrict__ Av, const float* __restrict__ B,
       const float* __restrict__ bias,
       const float* __restrict__ g_, const float* __restrict__ b_,
       const float* __restrict__ m_, const float* __restrict__ v_,
       const float* __restrict__ scp,
       void* __restrict__ outv, int K, int Nc) {
    __shared__ float As[64][33];
    __shared__ float Bs[32][64];
    const int tid = threadIdx.x;
    const int row0 = blockIdx.x * 64;
    const int col0 = blockIdx.y * 64;
    float acc[4][4] = {};
    const int tx = tid & 15, ty = tid >> 4;
    for (int k0 = 0; k0 < K; k0 += 32) {
#pragma unroll
        for (int p = 0; p < 2; ++p) {
            int idx = p * 256 + tid;
            {
                int r = idx >> 3, c = (idx & 7) << 2;
                size_t aoff = (size_t)(row0 + r) * K + k0 + c;
                float4 va = *(const float4*)((const float*)Av + aoff);
                As[r][c + 0] = va.x; As[r][c + 1] = va.y;
                As[r][c + 2] = va.z; As[r][c + 3] = va.w;
            }
            {
                int kr = idx >> 4, cc = (idx & 15) << 2;
                *(float4*)&Bs[kr][cc] =
                    *(const float4*)(B + (size_t)(k0 + kr) * Nc + col0 + cc);
            }
        }
        __syncthreads();
#pragma unroll
        for (int k = 0; k < 32; ++k) {
            float4 bv = *(const float4*)&Bs[k][tx << 2];
            float a0 = As[ty * 4 + 0][k];
            float a1 = As[ty * 4 + 1][k];
            float a2 = As[ty * 4 + 2][k];
            float a3 = As[ty * 4 + 3][k];
            acc[0][0] += a0 * bv.x; acc[0][1] += a0 * bv.y; acc[0][2] += a0 * bv.z; acc[0][3] += a0 * bv.w;
            acc[1][0] += a1 * bv.x; acc[1][1] += a1 * bv.y; acc[1][2] += a1 * bv.z; acc[1][3] += a1 * bv.w;
            acc[2][0] += a2 * bv.x; acc[2][1] += a2 * bv.y; acc[2][2] += a2 * bv.z; acc[2][3] += a2 * bv.w;
            acc[3][0] += a3 * bv.x; acc[3][1] += a3 * bv.y; acc[3][2] += a3 * bv.z; acc[3][3] += a3 * bv.w;
        }
        __syncthreads();
    }
#pragma unroll
    for (int j = 0; j < 4; ++j) {
        int gr = row0 + ty * 4 + j;
        float vals[4];
#pragma unroll
        for (int lx = 0; lx < 4; ++lx) {
            int gc = col0 + (tx << 2) + lx;
            float val = acc[j][lx];
            if (EMODE == E_BIAS) {
                float v = val + bias[gc];
                if (scp) v *= scp[gc];
                vals[lx] = v;
            } else {
                float y = val + bias[gc];
                float s = g_[gc] * rsqrtf(v_[gc] + 1e-5f);
                y = (y - m_[gc]) * s + b_[gc];
                vals[lx] = fmaxf(y, 0.f);
            }
        }
        *(float4*)((float*)outv + (size_t)gr * Nc + col0 + (tx << 2)) =
            make_float4(vals[0], vals[1], vals[2], vals[3]);
    }
}

// ---------------- final head ----------------
__global__ void k_final(const float* __restrict__ vn, const float* __restrict__ pW1,
                        const float* __restrict__ pb1, const float* __restrict__ pW2,
                        const float* __restrict__ pb2, float* __restrict__ out) {
    int g = blockIdx.x;
    int j = threadIdx.x;
    __shared__ float vrow[HH];
    __shared__ float red[HH];
    vrow[j] = vn[(size_t)g * HH + j];
    __syncthreads();
    float acc = pb1[j];
    for (int k = 0; k < HH; ++k) acc = fmaf(vrow[k], pW1[k * HH + j], acc);
    red[j] = fmaxf(acc, 0.f) * pW2[j];
    __syncthreads();
    for (int s = 64; s > 0; s >>= 1) {
        if (j < s) red[j] += red[j + s];
        __syncthreads();
    }
    if (j == 0) out[g] = fminf(fmaxf(red[0] + pb2[0], 0.f), 50.f);
}

extern "C" void kernel_launch(void* const* d_in, const int* in_sizes, int n_in,
                              void* d_out, int out_size, void* d_ws, size_t ws_size,
                              hipStream_t stream) {
    const int*   x        = (const int*)  d_in[0];
    const int*   ei       = (const int*)  d_in[1];
    const int*   ea       = (const int*)  d_in[2];
    const int*   batch    = (const int*)  d_in[3];
    const float* atom_emb = (const float*)d_in[4];
    const float* vn_emb   = (const float*)d_in[5];
    const float* bond_emb = (const float*)d_in[6];
    const float* conv_eps = (const float*)d_in[7];
    const float* conv_W1  = (const float*)d_in[8];
    const float* conv_b1  = (const float*)d_in[9];
    const float* cbn_g    = (const float*)d_in[10];
    const float* cbn_b    = (const float*)d_in[11];
    const float* cbn_m    = (const float*)d_in[12];
    const float* cbn_v    = (const float*)d_in[13];
    const float* conv_W2  = (const float*)d_in[14];
    const float* conv_b2  = (const float*)d_in[15];
    const float* vn1_W    = (const float*)d_in[16];
    const float* vn1_b    = (const float*)d_in[17];
    const float* vn1_g    = (const float*)d_in[18];
    const float* vn1_be   = (const float*)d_in[19];
    const float* vn1_m    = (const float*)d_in[20];
    const float* vn1_v    = (const float*)d_in[21];
    const float* vn2_W    = (const float*)d_in[22];
    const float* vn2_b    = (const float*)d_in[23];
    const float* vn2_g    = (const float*)d_in[24];
    const float* vn2_be   = (const float*)d_in[25];
    const float* vn2_m    = (const float*)d_in[26];
    const float* vn2_v    = (const float*)d_in[27];
    const float* pW1      = (const float*)d_in[28];
    const float* pb1      = (const float*)d_in[29];
    const float* pW2      = (const float*)d_in[30];
    const float* pb2      = (const float*)d_in[31];

    // ---- workspace layout (~165 MB) ----
    char* base = (char*)d_ws;
    ushort*   h16a   = (ushort*)base;                                 // NN*HH fp16
    ushort*   h16b   = h16a + (size_t)NN * HH;                        // NN*HH fp16
    unsigned* packed = (unsigned*)(h16b + (size_t)NN * HH);           // EE u32
    int*      rowptr = (int*)(packed + EE);                           // NN+4
    int*      fill   = rowptr + NN + 4;                               // NN
    ushort*   ct16   = (ushort*)(fill + NN);                          // 512*HH fp16
    int*      sums   = (int*)(ct16 + 512 * HH);                       // 256
    ushort*   W1t    = (ushort*)(sums + 256);                         // 256*128
    ushort*   W2t    = W1t + 256 * 128;                               // 128*256
    ushort*   W3t    = W2t + 128 * 256;                               // 256*128
    float*    ZA     = (float*)(W3t + 256 * 128);                     // 256
    float*    ZB     = ZA + 256;
    float*    TA     = ZB + 256;
    float*    TB     = TA + 256;
    float*    S3     = TB + 256;
    float*    vn     = S3 + 256;                                      // GG*HH f32
    ushort*   vn16   = (ushort*)(vn + (size_t)GG * HH);               // GG*HH fp16
    float*    vnW    = (float*)(vn16 + (size_t)GG * HH);              // GG*256
    float*    pooled = vnW + (size_t)GG * 256;                        // GG*256
    float*    out    = (float*)d_out;

    // ---- setup ----
    k_zero<<<256, 256, 0, stream>>>((float*)fill);
    k_hist<<<EE / 256, 256, 0, stream>>>(ei, fill);
    k_scan1<<<256, 256, 0, stream>>>(fill, rowptr, sums);
    k_scan2<<<1, 256, 0, stream>>>(sums);
    k_scan3<<<256, 256, 0, stream>>>(rowptr, sums, fill);
    k_scatter<<<EE / 256, 256, 0, stream>>>(ei, ea, fill, packed);
    k_atom<<<NN * 32 / 256, 256, 0, stream>>>(x, atom_emb, h16a);
    k_init_vn<<<GG * HH / 4 / 256, 256, 0, stream>>>(vn_emb, vn);

    for (int i = 0; i < 4; ++i) {
        ushort* hin  = (i & 1) ? h16b : h16a;
        ushort* hout = (i & 1) ? h16a : h16b;

        k_setup<<<3521, 256, 0, stream>>>(
            bond_emb + (size_t)i * FBc * VBc * HH, ct16,
            conv_b1 + i * 256, cbn_g + i * 256, cbn_b + i * 256,
            cbn_m + i * 256, cbn_v + i * 256,
            vn1_g + i * 256, vn1_be + i * 256, vn1_m + i * 256, vn1_v + i * 256,
            ZA, ZB, TA, TB, S3,
            conv_W1 + (size_t)i * HH * 256, W1t,
            conv_W2 + (size_t)i * 256 * HH, W2t,
            vn1_W + (size_t)i * 256 * 256 + 128 * 256, W3t,
            vn, vn16, pooled);

        // GEMM3a: vnW' = (vn @ vn1_W[:128] + vn1_b) * s3
        {
            dim3 g3(GG / 64, 4);
            gemm_k<E_BIAS><<<g3, 256, 0, stream>>>(
                vn, vn1_W + (size_t)i * 256 * 256, vn1_b + i * 256,
                nullptr, nullptr, nullptr, nullptr, S3, vnW, HH, 256);
        }

        // mega-kernel v6 (fused gather + MLP + pool)
        k_conv<<<NN / 64, 256, 0, stream>>>(
            hin, hout, rowptr, packed, ct16,
            W1t, W2t, W3t, batch, vn16, vnW, conv_eps + i,
            ZA, ZB, conv_b2 + i * HH, TA, TB, pooled);

        // GEMM4: vn = relu(bn(pooled @ vn2_W + vn2_b))
        {
            dim3 g4(GG / 64, 2);
            gemm_k<E_BNRELU><<<g4, 256, 0, stream>>>(
                pooled, vn2_W + (size_t)i * 256 * HH, vn2_b + i * HH,
                vn2_g + i * HH, vn2_be + i * HH, vn2_m + i * HH, vn2_v + i * HH,
                nullptr, vn, 256, HH);
        }
    }
    k_final<<<GG, 128, 0, stream>>>(vn, pW1, pb1, pW2, pb2, out);
}